// Round 11
// baseline (984.031 us; speedup 1.0000x reference)
//
#include <hip/hip_runtime.h>

typedef __bf16 bf16x8 __attribute__((ext_vector_type(8)));
typedef unsigned short u16x8 __attribute__((ext_vector_type(8)));
typedef float  f32x4  __attribute__((ext_vector_type(4)));

#define BATCH_ 32768
#define VOC 4094
#define LGT_STRIDE 8188   // ushorts per out row (4094 f32)

__device__ inline unsigned short f2bf(float f) {
    unsigned int u = __builtin_bit_cast(unsigned int, f);
    unsigned int r = u + 0x7FFFu + ((u >> 16) & 1u);
    return (unsigned short)(r >> 16);
}
__device__ inline float bf2f(unsigned short u) {
    unsigned int v = ((unsigned int)u) << 16;
    return __builtin_bit_cast(float, v);
}
__device__ inline f32x4 mfma16(bf16x8 a, bf16x8 b, f32x4 c) {
    return __builtin_amdgcn_mfma_f32_16x16x32_bf16(a, b, c, 0, 0, 0);
}
__device__ inline void gload16(const void* g, void* l) {
    __builtin_amdgcn_global_load_lds(
        (const __attribute__((address_space(1))) void*)(g),
        (__attribute__((address_space(3))) void*)(l),
        16, 0, 0);
}
__device__ inline bf16x8 pack8(float4 a, float4 b) {
    u16x8 u;
    u[0] = f2bf(a.x); u[1] = f2bf(a.y); u[2] = f2bf(a.z); u[3] = f2bf(a.w);
    u[4] = f2bf(b.x); u[5] = f2bf(b.y); u[6] = f2bf(b.z); u[7] = f2bf(b.w);
    return __builtin_bit_cast(bf16x8, u);
}

// ---------------- K0: weight prep -> pre-swizzled 16KB chunk images (BK=64) ----------------
__global__ __launch_bounds__(256) void k_prep(
    const float* __restrict__ comb_W, const float* __restrict__ W_ih,
    const float* __restrict__ W_hh, const float* __restrict__ out_W,
    const float* __restrict__ b_ih, const float* __restrict__ b_hh,
    const float* __restrict__ out_b,
    unsigned short* __restrict__ cwb, unsigned short* __restrict__ wg2,
    unsigned short* __restrict__ owb, float* __restrict__ bg,
    float* __restrict__ obp) {
    int i = blockIdx.x * 256 + threadIdx.x;      // grid covers 1,048,576
    if (i < 512 * 768) {
        int n = i / 768, k = i - n * 768;
        int by = n >> 7, r = n & 127, kc = k >> 6, kl = k & 63;
        int dst = (by * 12 + kc) * 8192 + r * 64 + (((kl >> 3) ^ (r & 7)) << 3) + (kl & 7);
        cwb[dst] = f2bf(comb_W[i]);
    }
    if (i < 1024 * 768) {
        int row = i / 768, k = i - row * 768;
        int hgrp = row >> 6, g = (row >> 4) & 3, hl = row & 15;
        int h = hgrp * 16 + hl;
        float v;
        if (g == 0) v = (k < 512) ? W_ih[(size_t)h * 512 + k] : W_hh[(size_t)h * 256 + (k - 512)];
        else if (g == 1) v = (k < 512) ? W_ih[(size_t)(256 + h) * 512 + k] : W_hh[(size_t)(256 + h) * 256 + (k - 512)];
        else if (g == 2) v = (k < 512) ? W_ih[(size_t)(512 + h) * 512 + k] : 0.f;
        else v = (k < 512) ? 0.f : W_hh[(size_t)(512 + h) * 256 + (k - 512)];
        int by = row >> 7, r = row & 127, kc = k >> 6, kl = k & 63;
        int dst = (by * 12 + kc) * 8192 + r * 64 + (((kl >> 3) ^ (r & 7)) << 3) + (kl & 7);
        wg2[dst] = f2bf(v);
    }
    if (i < 4096 * 256) {
        int n = i >> 8, k = i & 255;
        int by = n >> 7, r = n & 127, kc = k >> 6, kl = k & 63;
        int dst = (by * 4 + kc) * 8192 + r * 64 + (((kl >> 3) ^ (r & 7)) << 3) + (kl & 7);
        owb[dst] = (n < VOC) ? f2bf(out_W[i]) : (unsigned short)0;
    }
    if (i < 1024) {
        float v = (i < 512) ? (b_ih[i] + b_hh[i]) : ((i < 768) ? b_ih[i] : b_hh[i - 256]);
        bg[i] = v;
    }
    if (i < 4096) obp[i] = (i < VOC) ? out_b[i] : -1.0e30f;
}

// ---------------- K1: attention via MFMA (64 batch rows / block, 4 waves) ----------------
// phase1: u[b][m] = h@aW2^T + ab   (1 tile/wave)
// phase2: scores = enc@aW1^T; softmax over m (2 shfl_xor); wsum[b][m] += w (LDS atomic)
// phase3: c[b][:] = sum_m wsum*enc; write c,h (bf16) + emb gather
__global__ __launch_bounds__(256) void k_attn(
    const int* __restrict__ dw, const float* __restrict__ hidden,
    const float* __restrict__ enc, const float* __restrict__ emb,
    const float* __restrict__ aW, const float* __restrict__ ab,
    unsigned short* __restrict__ xcat, unsigned short* __restrict__ xh) {
    __shared__ __align__(16) unsigned short sA1[16 * 264];  // aW[:, :256] bf16, rows>=9 zero
    __shared__ __align__(16) unsigned short sA2[16 * 264];  // aW[:, 256:] bf16
    __shared__ float sU[64][17];
    __shared__ float sW[64][17];
    __shared__ float sAB[16];
    int tid = threadIdx.x, w = tid >> 6, lane = tid & 63;
    int lo = lane & 15, hi = lane >> 4;
    int B0 = blockIdx.x * 64;

    for (int i = tid; i < 16 * 256; i += 256) {
        int m = i >> 8, k = i & 255;
        float v1 = (m < 9) ? aW[m * 512 + k] : 0.f;
        float v2 = (m < 9) ? aW[m * 512 + 256 + k] : 0.f;
        sA1[m * 264 + k] = f2bf(v1);
        sA2[m * 264 + k] = f2bf(v2);
    }
    if (tid < 16) sAB[tid] = (tid < 9) ? ab[tid] : 0.f;
    if (tid < 64) {
#pragma unroll
        for (int m = 0; m < 16; m++) sW[tid][m] = 0.f;
    }
    __syncthreads();

    // ---- phase 1: u tile (A=aW2, B=h rows; b = B0 + w*16 + lo) ----
    {
        const float* hrow = hidden + (size_t)(B0 + w * 16 + lo) * 256 + 8 * hi;
        f32x4 uacc = {};
#pragma unroll
        for (int ks = 0; ks < 8; ks++) {
            float4 f0 = *(const float4*)(hrow + ks * 32);
            float4 f1 = *(const float4*)(hrow + ks * 32 + 4);
            bf16x8 Bf = pack8(f0, f1);
            bf16x8 Af = *(const bf16x8*)(sA2 + lo * 264 + ks * 32 + 8 * hi);
            uacc = mfma16(Af, Bf, uacc);
        }
#pragma unroll
        for (int r = 0; r < 4; r++) {
            int m = hi * 4 + r;
            sU[w * 16 + lo][m] = uacc[r] + sAB[m];
        }
    }
    __syncthreads();

    // ---- phase 2: scores + softmax + wsum (wave w owns rows [w*144, w*144+144)) ----
    bf16x8 Asc[8];
#pragma unroll
    for (int ks = 0; ks < 8; ks++)
        Asc[ks] = *(const bf16x8*)(sA1 + lo * 264 + ks * 32 + 8 * hi);
    const float* encF = enc + (size_t)B0 * 9 * 256;
#pragma unroll
    for (int t = 0; t < 9; t++) {
        int rowloc = w * 144 + t * 16 + lo;        // flat (b,l) within block
        const float* er = encF + (size_t)rowloc * 256 + 8 * hi;
        f32x4 acc = {};
#pragma unroll
        for (int ks = 0; ks < 8; ks++) {
            float4 f0 = *(const float4*)(er + ks * 32);
            float4 f1 = *(const float4*)(er + ks * 32 + 4);
            bf16x8 Bf = pack8(f0, f1);
            acc = mfma16(Asc[ks], Bf, acc);
        }
        int bloc = rowloc / 9;
        float s[4];
        float mx = -1.0e30f;
#pragma unroll
        for (int r = 0; r < 4; r++) {
            int m = hi * 4 + r;
            s[r] = acc[r] + sU[bloc][m];
            if (m < 9) mx = fmaxf(mx, s[r]);
        }
        mx = fmaxf(mx, __shfl_xor(mx, 16));
        mx = fmaxf(mx, __shfl_xor(mx, 32));
        float ex[4], sm = 0.f;
#pragma unroll
        for (int r = 0; r < 4; r++) {
            int m = hi * 4 + r;
            ex[r] = (m < 9) ? __expf(s[r] - mx) : 0.f;
            sm += ex[r];
        }
        sm += __shfl_xor(sm, 16);
        sm += __shfl_xor(sm, 32);
        float inv = 1.f / sm;
#pragma unroll
        for (int r = 0; r < 4; r++) {
            int m = hi * 4 + r;
            if (m < 9) atomicAdd(&sW[bloc][m], ex[r] * inv);
        }
    }
    __syncthreads();

    // ---- phase 3: c = sum_m wsum*enc; write c, h (bf16); emb gather ----
    int b = tid >> 2, q = tid & 3;                 // 64 b-rows x 4 quarters (64 h each)
    float ws[9];
#pragma unroll
    for (int m = 0; m < 9; m++) ws[m] = sW[b][m];
    const float* encB = enc + (size_t)(B0 + b) * 9 * 256 + q * 64;
    const float* hp = hidden + (size_t)(B0 + b) * 256 + q * 64;
    unsigned short* xc = xcat + (size_t)(B0 + b) * 768 + 512 + q * 64;
    unsigned short* xhp = xh + (size_t)(B0 + b) * 768 + 512 + q * 64;
#pragma unroll
    for (int g = 0; g < 16; g++) {
        float4 c = {0.f, 0.f, 0.f, 0.f};
#pragma unroll
        for (int m = 0; m < 9; m++) {
            float4 e4 = *(const float4*)(encB + m * 256 + g * 4);
            c.x += ws[m] * e4.x; c.y += ws[m] * e4.y;
            c.z += ws[m] * e4.z; c.w += ws[m] * e4.w;
        }
        ushort4 cb; cb.x = f2bf(c.x); cb.y = f2bf(c.y); cb.z = f2bf(c.z); cb.w = f2bf(c.w);
        *(ushort4*)(xc + g * 4) = cb;
        float4 h4 = *(const float4*)(hp + g * 4);
        ushort4 hb; hb.x = f2bf(h4.x); hb.y = f2bf(h4.y); hb.z = f2bf(h4.z); hb.w = f2bf(h4.w);
        *(ushort4*)(xhp + g * 4) = hb;
    }
    int word = dw[B0 + b];
    const float* er2 = emb + (size_t)word * 512 + q * 128;
    unsigned short* xe = xcat + (size_t)(B0 + b) * 768 + q * 128;
#pragma unroll
    for (int g = 0; g < 32; g++) {
        float4 e4 = *(const float4*)(er2 + g * 4);
        ushort4 eb; eb.x = f2bf(e4.x); eb.y = f2bf(e4.y); eb.z = f2bf(e4.z); eb.w = f2bf(e4.w);
        *(ushort4*)(xe + g * 4) = eb;
    }
}

// ---------------- K2: x = relu(xcat @ comb_W^T + comb_b) -> xh[:,0:512] ----------------
// grid 1024 = 8 xcd x 32 bx x 4 by; tile 128M x 128N; BK=64 dbuf (2x16KB), M-rep 2.
__global__ __launch_bounds__(256, 4) void k_combine(
    const unsigned short* __restrict__ xcat, const unsigned short* __restrict__ cwb,
    const float* __restrict__ comb_b, unsigned short* __restrict__ xh) {
    __shared__ __align__(16) char smem[32768];
    int wgid = blockIdx.x;
    int xcd = wgid & 7, slot = wgid >> 3;
    int bx = xcd * 32 + (slot & 31), by = slot >> 5;     // bx<256, by<4
    int tid = threadIdx.x, w = tid >> 6, lane = tid & 63;
    int lo = lane & 15, hi = lane >> 4;
    int bm0 = bx * 128, n0 = by * 128;
    const __bf16* A = (const __bf16*)xcat;
    const char* gb = (const char*)cwb + (size_t)by * 12 * 16384;
    size_t ar = (size_t)(bm0 + w * 32 + lo) * 768 + 8 * hi;
    f32x4 acc[2][8] = {};
    bf16x8 Afb[2][2][2];
#pragma unroll
    for (int mf = 0; mf < 2; mf++)
#pragma unroll
        for (int ks = 0; ks < 2; ks++)
            Afb[0][mf][ks] = *(const bf16x8*)(A + ar + mf * 16 * 768 + ks * 32);
    for (int it = 0; it < 4; it++) {
        int uo = (w * 4 + it) << 10;
        gload16(gb + uo + lane * 16, smem + uo);
    }
    __syncthreads();
#pragma unroll
    for (int c = 0; c < 12; c++) {
        int cur = c & 1;
        if (c < 11) {
            const char* gc = gb + (size_t)(c + 1) * 16384;
            char* lb = smem + (cur ^ 1) * 16384;
            for (int it = 0; it < 4; it++) {
                int uo = (w * 4 + it) << 10;
                gload16(gc + uo + lane * 16, lb + uo);
            }
#pragma unroll
            for (int mf = 0; mf < 2; mf++)
#pragma unroll
                for (int ks = 0; ks < 2; ks++)
                    Afb[cur ^ 1][mf][ks] = *(const bf16x8*)(A + ar + mf * 16 * 768 + (c + 1) * 64 + ks * 32);
        }
        const char* cb = smem + cur * 16384;
#pragma unroll
        for (int ks = 0; ks < 2; ks++)
#pragma unroll
            for (int nf = 0; nf < 8; nf++) {
                int row = nf * 16 + lo;
                bf16x8 bfr = *(const bf16x8*)(cb + row * 128 + (((ks * 4 + hi) ^ (lo & 7)) << 4));
                acc[0][nf] = mfma16(Afb[cur][0][ks], bfr, acc[0][nf]);
                acc[1][nf] = mfma16(Afb[cur][1][ks], bfr, acc[1][nf]);
            }
        __syncthreads();
    }
#pragma unroll
    for (int mf = 0; mf < 2; mf++)
#pragma unroll
        for (int nf = 0; nf < 8; nf++) {
            int col = n0 + nf * 16 + lo;
            float cb = comb_b[col];
#pragma unroll
            for (int r = 0; r < 4; r++) {
                int row = bm0 + w * 32 + mf * 16 + hi * 4 + r;
                xh[(size_t)row * 768 + col] = f2bf(fmaxf(acc[mf][nf][r] + cb, 0.f));
            }
        }
}

// ---------------- K3: GRU gates GEMM (interleaved wg2) + in-register epilogue ----------------
// grid 2048 = 8 xcd x 32 bx x 8 by; tile 128M x 128N (32h x 4gates); BK=64 dbuf, M-rep 2.
__global__ __launch_bounds__(256, 4) void k_gru(
    const unsigned short* __restrict__ xh, const unsigned short* __restrict__ wg2,
    const float* __restrict__ bg, const float* __restrict__ hidden,
    float* __restrict__ hnew_out, unsigned short* __restrict__ hnb) {
    __shared__ __align__(16) char smem[32768];
    int wgid = blockIdx.x;
    int xcd = wgid & 7, slot = wgid >> 3;
    int bx = xcd * 32 + (slot & 31), by = slot >> 5;     // bx<256, by<8
    int tid = threadIdx.x, w = tid >> 6, lane = tid & 63;
    int lo = lane & 15, hi = lane >> 4;
    int bm0 = bx * 128;
    int h00 = by * 32;
    const __bf16* A = (const __bf16*)xh;
    const char* gb = (const char*)wg2 + (size_t)by * 12 * 16384;
    size_t ar = (size_t)(bm0 + w * 32 + lo) * 768 + 8 * hi;
    f32x4 acc[2][8] = {};
    bf16x8 Afb[2][2][2];
#pragma unroll
    for (int mf = 0; mf < 2; mf++)
#pragma unroll
        for (int ks = 0; ks < 2; ks++)
            Afb[0][mf][ks] = *(const bf16x8*)(A + ar + mf * 16 * 768 + ks * 32);
    for (int it = 0; it < 4; it++) {
        int uo = (w * 4 + it) << 10;
        gload16(gb + uo + lane * 16, smem + uo);
    }
    __syncthreads();
#pragma unroll
    for (int c = 0; c < 12; c++) {
        int cur = c & 1;
        if (c < 11) {
            const char* gc = gb + (size_t)(c + 1) * 16384;
            char* lb = smem + (cur ^ 1) * 16384;
            for (int it = 0; it < 4; it++) {
                int uo = (w * 4 + it) << 10;
                gload16(gc + uo + lane * 16, lb + uo);
            }
#pragma unroll
            for (int mf = 0; mf < 2; mf++)
#pragma unroll
                for (int ks = 0; ks < 2; ks++)
                    Afb[cur ^ 1][mf][ks] = *(const bf16x8*)(A + ar + mf * 16 * 768 + (c + 1) * 64 + ks * 32);
        }
        const char* cb = smem + cur * 16384;
#pragma unroll
        for (int ks = 0; ks < 2; ks++)
#pragma unroll
            for (int nf = 0; nf < 8; nf++) {
                int row = nf * 16 + lo;
                bf16x8 bfr = *(const bf16x8*)(cb + row * 128 + (((ks * 4 + hi) ^ (lo & 7)) << 4));
                acc[0][nf] = mfma16(Afb[cur][0][ks], bfr, acc[0][nf]);
                acc[1][nf] = mfma16(Afb[cur][1][ks], bfr, acc[1][nf]);
            }
        __syncthreads();
    }
    // epilogue: acc[mf][hgrp*4 + g] holds gate g for h-col = h00 + hgrp*16 + lo
#pragma unroll
    for (int mf = 0; mf < 2; mf++)
#pragma unroll
        for (int hgrp = 0; hgrp < 2; hgrp++) {
            int col = h00 + hgrp * 16 + lo;
            float br = bg[col], bz = bg[256 + col], bi = bg[512 + col], bh = bg[768 + col];
#pragma unroll
            for (int r = 0; r < 4; r++) {
                int row = bm0 + w * 32 + mf * 16 + hi * 4 + r;
                float rr = 1.f / (1.f + __expf(-(acc[mf][hgrp * 4 + 0][r] + br)));
                float zz = 1.f / (1.f + __expf(-(acc[mf][hgrp * 4 + 1][r] + bz)));
                float nn = tanhf(acc[mf][hgrp * 4 + 2][r] + bi + rr * (acc[mf][hgrp * 4 + 3][r] + bh));
                float hp = hidden[(size_t)row * 256 + col];
                float hn = zz * (hp - nn) + nn;
                hnew_out[(size_t)row * 256 + col] = hn;
                hnb[(size_t)row * 256 + col] = f2bf(hn);
            }
        }
}

// ---------------- K4: vocab GEMM (once): bf16 logits into out rows + psum ----------------
// grid 8192 = 8 xcd x 32 bx x 32 by; tile 128M x 128N; K=256 = 4 BK=64 dbuf chunks, M-rep 2.
__global__ __launch_bounds__(256, 4) void k_logit(
    const unsigned short* __restrict__ hnb, const unsigned short* __restrict__ owb,
    const float* __restrict__ obp, unsigned short* __restrict__ lgt,
    float* __restrict__ psum) {
    __shared__ __align__(16) char smem[34816];   // dbuf 2x16KB; T [128][136] ushort = 34816B
    int wgid = blockIdx.x;
    int xcd = wgid & 7, slot = wgid >> 3;
    int bx = xcd * 32 + (slot & 31), by = slot >> 5;     // bx<256, by<32
    int tid = threadIdx.x, w = tid >> 6, lane = tid & 63;
    int lo = lane & 15, hi = lane >> 4;
    int bm0 = bx * 128, n0 = by * 128;
    const __bf16* A = (const __bf16*)hnb;
    const char* gb = (const char*)owb + (size_t)by * 4 * 16384;
    size_t ar = (size_t)(bm0 + w * 32 + lo) * 256 + 8 * hi;
    f32x4 acc[2][8] = {};
    bf16x8 Afb[2][2][2];
#pragma unroll
    for (int mf = 0; mf < 2; mf++)
#pragma unroll
        for (int ks = 0; ks < 2; ks++)
            Afb[0][mf][ks] = *(const bf16x8*)(A + ar + mf * 16 * 256 + ks * 32);
    for (int it = 0; it < 4; it++) {
        int uo = (w * 4 + it) << 10;
        gload16(gb + uo + lane * 16, smem + uo);
    }
    __syncthreads();
#pragma unroll
    for (int c = 0; c < 4; c++) {
        int cur = c & 1;
        if (c < 3) {
            const char* gc = gb + (size_t)(c + 1) * 16384;
            char* lb = smem + (cur ^ 1) * 16384;
            for (int it = 0; it < 4; it++) {
                int uo = (w * 4 + it) << 10;
                gload16(gc + uo + lane * 16, lb + uo);
            }
#pragma unroll
            for (int mf = 0; mf < 2; mf++)
#pragma unroll
                for (int ks = 0; ks < 2; ks++)
                    Afb[cur ^ 1][mf][ks] = *(const bf16x8*)(A + ar + mf * 16 * 256 + (c + 1) * 64 + ks * 32);
        }
        const char* cb = smem + cur * 16384;
#pragma unroll
        for (int ks = 0; ks < 2; ks++)
#pragma unroll
            for (int nf = 0; nf < 8; nf++) {
                int row = nf * 16 + lo;
                bf16x8 bfr = *(const bf16x8*)(cb + row * 128 + (((ks * 4 + hi) ^ (lo & 7)) << 4));
                acc[0][nf] = mfma16(Afb[cur][0][ks], bfr, acc[0][nf]);
                acc[1][nf] = mfma16(Afb[cur][1][ks], bfr, acc[1][nf]);
            }
        __syncthreads();
    }

    unsigned short* T = (unsigned short*)smem;   // [128][136]
    float se[2][4] = {};
#pragma unroll
    for (int mf = 0; mf < 2; mf++)
#pragma unroll
        for (int nf = 0; nf < 8; nf++) {
            int col = n0 + nf * 16 + lo;
            float ob = obp[col];
#pragma unroll
            for (int r = 0; r < 4; r++) {
                float lg = acc[mf][nf][r] + ob;
                se[mf][r] += __expf(lg);
                T[(w * 32 + mf * 16 + hi * 4 + r) * 136 + nf * 16 + lo] = f2bf(lg);
            }
        }
#pragma unroll
    for (int mf = 0; mf < 2; mf++)
#pragma unroll
        for (int r = 0; r < 4; r++) {
            float v = se[mf][r];
            v += __shfl_xor(v, 1); v += __shfl_xor(v, 2);
            v += __shfl_xor(v, 4); v += __shfl_xor(v, 8);
            se[mf][r] = v;
        }
    if (lo == 0) {
#pragma unroll
        for (int mf = 0; mf < 2; mf++)
#pragma unroll
            for (int r = 0; r < 4; r++)
                psum[(size_t)by * BATCH_ + bm0 + w * 32 + mf * 16 + hi * 4 + r] = se[mf][r];
    }
    __syncthreads();
#pragma unroll
    for (int it = 0; it < 8; it++) {
        int t = it * 256 + tid;
        int row = t >> 4, ch = t & 15;
        ushort4 a = *(ushort4*)(T + row * 136 + ch * 8);
        ushort4 b = *(ushort4*)(T + row * 136 + ch * 8 + 4);
        size_t base = (size_t)(bm0 + row) * LGT_STRIDE + n0 + ch * 8;
        *(ushort4*)(lgt + base) = a;
        *(ushort4*)(lgt + base + 4) = b;
    }
}

// ---------------- K5: fused lse + streaming out[b][v] = bf16logit - lse (in-place) ----------------
__global__ __launch_bounds__(256) void k_out2(
    const float* __restrict__ psum, float* __restrict__ out) {
    __shared__ float sl;
    int b = blockIdx.x, tid = threadIdx.x;
    const unsigned short* rowp = (const unsigned short*)(out + (size_t)b * VOC);
    ushort4 a0 = *(const ushort4*)(rowp + tid * 8);
    ushort4 b0 = *(const ushort4*)(rowp + tid * 8 + 4);
    ushort4 a1 = *(const ushort4*)(rowp + 2048 + tid * 8);
    ushort4 b1 = *(const ushort4*)(rowp + 2048 + tid * 8 + 4);
    if (tid < 32) {
        float v = psum[(size_t)tid * BATCH_ + b];
        v += __shfl_xor(v, 1); v += __shfl_xor(v, 2); v += __shfl_xor(v, 4);
        v += __shfl_xor(v, 8); v += __shfl_xor(v, 16);
        if (tid == 0) sl = __logf(v);
    }
    __syncthreads();      // lse ready + all reads done before in-place overwrite
    float l = sl;
    float* orow = out + (size_t)b * VOC;
    int v0 = tid * 8;
    {
        float2 p;
        p.x = bf2f(a0.x) - l; p.y = bf2f(a0.y) - l; *(float2*)(orow + v0) = p;
        p.x = bf2f(a0.z) - l; p.y = bf2f(a0.w) - l; *(float2*)(orow + v0 + 2) = p;
        p.x = bf2f(b0.x) - l; p.y = bf2f(b0.y) - l; *(float2*)(orow + v0 + 4) = p;
        p.x = bf2f(b0.z) - l; p.y = bf2f(b0.w) - l; *(float2*)(orow + v0 + 6) = p;
    }
    int v1 = 2048 + tid * 8;
    {
        float2 p;
        p.x = bf2f(a1.x) - l; p.y = bf2f(a1.y) - l;
        if (v1 + 1 < VOC) *(float2*)(orow + v1) = p;
        p.x = bf2f(a1.z) - l; p.y = bf2f(a1.w) - l;
        if (v1 + 3 < VOC) *(float2*)(orow + v1 + 2) = p;
        p.x = bf2f(b1.x) - l; p.y = bf2f(b1.y) - l;
        if (v1 + 5 < VOC) *(float2*)(orow + v1 + 4) = p;
        p.x = bf2f(b1.z) - l; p.y = bf2f(b1.w) - l;
        if (v1 + 7 < VOC) *(float2*)(orow + v1 + 6) = p;
    }
}

extern "C" void kernel_launch(void* const* d_in, const int* in_sizes, int n_in,
                              void* d_out, int out_size, void* d_ws, size_t ws_size,
                              hipStream_t stream) {
    const int*   dw      = (const int*)d_in[0];
    const float* hidden  = (const float*)d_in[1];
    const float* enc     = (const float*)d_in[2];
    const float* emb     = (const float*)d_in[3];
    const float* aW      = (const float*)d_in[4];
    const float* ab      = (const float*)d_in[5];
    const float* comb_W  = (const float*)d_in[6];
    const float* comb_b  = (const float*)d_in[7];
    const float* W_ih    = (const float*)d_in[8];
    const float* b_ih    = (const float*)d_in[9];
    const float* W_hh    = (const float*)d_in[10];
    const float* b_hh    = (const float*)d_in[11];
    const float* out_W   = (const float*)d_in[12];
    const float* out_b   = (const float*)d_in[13];

    float* out = (float*)d_out;
    float* hnew_out = out + (size_t)BATCH_ * VOC;

    unsigned short* xcat = (unsigned short*)d_ws;
    unsigned short* xh   = xcat + (size_t)BATCH_ * 768;
    unsigned short* hnb  = xh + (size_t)BATCH_ * 768;
    float* psum          = (float*)(hnb + (size_t)BATCH_ * 256);   // 32 * BATCH floats
    float* obp           = psum + (size_t)32 * BATCH_;             // 4096 floats
    unsigned short* cwb  = (unsigned short*)(obp + 4096);
    unsigned short* wg2  = cwb + 512 * 768;
    unsigned short* owb  = wg2 + 1024 * 768;
    float* bg            = (float*)(owb + 4096 * 256);

    k_prep<<<4096, 256, 0, stream>>>(comb_W, W_ih, W_hh, out_W, b_ih, b_hh, out_b,
                                     cwb, wg2, owb, bg, obp);
    k_attn<<<BATCH_ / 64, 256, 0, stream>>>(dw, hidden, enc, emb, aW, ab, xcat, xh);
    k_combine<<<1024, 256, 0, stream>>>(xcat, cwb, comb_b, xh);
    k_gru<<<2048, 256, 0, stream>>>(xh, wg2, bg, hidden, hnew_out, hnb);
    k_logit<<<8192, 256, 0, stream>>>(hnb, owb, obp, (unsigned short*)out, psum);
    k_out2<<<BATCH_, 256, 0, stream>>>(psum, out);
}

// Round 12
// 737.915 us; speedup vs baseline: 1.3335x; 1.3335x over previous
//
#include <hip/hip_runtime.h>

typedef __bf16 bf16x8 __attribute__((ext_vector_type(8)));
typedef unsigned short u16x8 __attribute__((ext_vector_type(8)));
typedef float  f32x4  __attribute__((ext_vector_type(4)));

#define BATCH_ 32768
#define VOC 4094
#define LGT_STRIDE 8188   // ushorts per out row (4094 f32)

__device__ inline unsigned short f2bf(float f) {
    unsigned int u = __builtin_bit_cast(unsigned int, f);
    unsigned int r = u + 0x7FFFu + ((u >> 16) & 1u);
    return (unsigned short)(r >> 16);
}
__device__ inline float bf2f(unsigned short u) {
    unsigned int v = ((unsigned int)u) << 16;
    return __builtin_bit_cast(float, v);
}
__device__ inline f32x4 mfma16(bf16x8 a, bf16x8 b, f32x4 c) {
    return __builtin_amdgcn_mfma_f32_16x16x32_bf16(a, b, c, 0, 0, 0);
}
__device__ inline void gload16(const void* g, void* l) {
    __builtin_amdgcn_global_load_lds(
        (const __attribute__((address_space(1))) void*)(g),
        (__attribute__((address_space(3))) void*)(l),
        16, 0, 0);
}
__device__ inline bf16x8 pack8(float4 a, float4 b) {
    u16x8 u;
    u[0] = f2bf(a.x); u[1] = f2bf(a.y); u[2] = f2bf(a.z); u[3] = f2bf(a.w);
    u[4] = f2bf(b.x); u[5] = f2bf(b.y); u[6] = f2bf(b.z); u[7] = f2bf(b.w);
    return __builtin_bit_cast(bf16x8, u);
}

// ---------------- K0: weight prep -> pre-swizzled 16KB chunk images (BK=64) ----------------
__global__ __launch_bounds__(256) void k_prep(
    const float* __restrict__ comb_W, const float* __restrict__ W_ih,
    const float* __restrict__ W_hh, const float* __restrict__ out_W,
    const float* __restrict__ b_ih, const float* __restrict__ b_hh,
    const float* __restrict__ out_b,
    unsigned short* __restrict__ cwb, unsigned short* __restrict__ wg2,
    unsigned short* __restrict__ owb, float* __restrict__ bg,
    float* __restrict__ obp) {
    int i = blockIdx.x * 256 + threadIdx.x;      // grid covers 1,048,576
    if (i < 512 * 768) {
        int n = i / 768, k = i - n * 768;
        int by = n >> 7, r = n & 127, kc = k >> 6, kl = k & 63;
        int dst = (by * 12 + kc) * 8192 + r * 64 + (((kl >> 3) ^ (r & 7)) << 3) + (kl & 7);
        cwb[dst] = f2bf(comb_W[i]);
    }
    if (i < 1024 * 768) {
        int row = i / 768, k = i - row * 768;
        int hgrp = row >> 6, g = (row >> 4) & 3, hl = row & 15;
        int h = hgrp * 16 + hl;
        float v;
        if (g == 0) v = (k < 512) ? W_ih[(size_t)h * 512 + k] : W_hh[(size_t)h * 256 + (k - 512)];
        else if (g == 1) v = (k < 512) ? W_ih[(size_t)(256 + h) * 512 + k] : W_hh[(size_t)(256 + h) * 256 + (k - 512)];
        else if (g == 2) v = (k < 512) ? W_ih[(size_t)(512 + h) * 512 + k] : 0.f;
        else v = (k < 512) ? 0.f : W_hh[(size_t)(512 + h) * 256 + (k - 512)];
        int by = row >> 7, r = row & 127, kc = k >> 6, kl = k & 63;
        int dst = (by * 12 + kc) * 8192 + r * 64 + (((kl >> 3) ^ (r & 7)) << 3) + (kl & 7);
        wg2[dst] = f2bf(v);
    }
    if (i < 4096 * 256) {
        int n = i >> 8, k = i & 255;
        int by = n >> 7, r = n & 127, kc = k >> 6, kl = k & 63;
        int dst = (by * 4 + kc) * 8192 + r * 64 + (((kl >> 3) ^ (r & 7)) << 3) + (kl & 7);
        owb[dst] = (n < VOC) ? f2bf(out_W[i]) : (unsigned short)0;
    }
    if (i < 1024) {
        float v = (i < 512) ? (b_ih[i] + b_hh[i]) : ((i < 768) ? b_ih[i] : b_hh[i - 256]);
        bg[i] = v;
    }
    if (i < 4096) obp[i] = (i < VOC) ? out_b[i] : -1.0e30f;
}

// ---------------- K1: attention (64 rows / block, 4 waves) ----------------
// phase1: u[b][m] = h@aW2^T + ab   (MFMA, 1 tile/wave)
// phase2: scores = enc@aW1^T (MFMA); softmax over m (2 shfl); wsum[b][m] += w (LDS atomic)
// phase3: wave-per-row coalesced: c = sum_m wsum*enc; write c,h (bf16) + emb gather
__global__ __launch_bounds__(256) void k_attn(
    const int* __restrict__ dw, const float* __restrict__ hidden,
    const float* __restrict__ enc, const float* __restrict__ emb,
    const float* __restrict__ aW, const float* __restrict__ ab,
    unsigned short* __restrict__ xcat, unsigned short* __restrict__ xh) {
    __shared__ __align__(16) unsigned short sA1[16 * 264];  // aW[:, :256] bf16, rows>=9 zero
    __shared__ __align__(16) unsigned short sA2[16 * 264];  // aW[:, 256:] bf16
    __shared__ float sU[64][17];
    __shared__ float sW[64][17];
    __shared__ float sAB[16];
    int tid = threadIdx.x, w = tid >> 6, lane = tid & 63;
    int lo = lane & 15, hi = lane >> 4;
    int B0 = blockIdx.x * 64;

    for (int i = tid; i < 16 * 256; i += 256) {
        int m = i >> 8, k = i & 255;
        float v1 = (m < 9) ? aW[m * 512 + k] : 0.f;
        float v2 = (m < 9) ? aW[m * 512 + 256 + k] : 0.f;
        sA1[m * 264 + k] = f2bf(v1);
        sA2[m * 264 + k] = f2bf(v2);
    }
    if (tid < 16) sAB[tid] = (tid < 9) ? ab[tid] : 0.f;
    if (tid < 64) {
#pragma unroll
        for (int m = 0; m < 16; m++) sW[tid][m] = 0.f;
    }
    __syncthreads();

    // ---- phase 1: u tile (A=aW2, B=h rows; b = B0 + w*16 + lo) ----
    {
        const float* hrow = hidden + (size_t)(B0 + w * 16 + lo) * 256 + 8 * hi;
        f32x4 uacc = {};
#pragma unroll
        for (int ks = 0; ks < 8; ks++) {
            float4 f0 = *(const float4*)(hrow + ks * 32);
            float4 f1 = *(const float4*)(hrow + ks * 32 + 4);
            bf16x8 Bf = pack8(f0, f1);
            bf16x8 Af = *(const bf16x8*)(sA2 + lo * 264 + ks * 32 + 8 * hi);
            uacc = mfma16(Af, Bf, uacc);
        }
#pragma unroll
        for (int r = 0; r < 4; r++) {
            int m = hi * 4 + r;
            sU[w * 16 + lo][m] = uacc[r] + sAB[m];
        }
    }
    __syncthreads();

    // ---- phase 2: scores + softmax + wsum (wave w owns rows [w*144, w*144+144)) ----
    bf16x8 Asc[8];
#pragma unroll
    for (int ks = 0; ks < 8; ks++)
        Asc[ks] = *(const bf16x8*)(sA1 + lo * 264 + ks * 32 + 8 * hi);
    const float* encF = enc + (size_t)B0 * 9 * 256;
#pragma unroll
    for (int t = 0; t < 9; t++) {
        int rowloc = w * 144 + t * 16 + lo;        // flat (b,l) within block
        const float* er = encF + (size_t)rowloc * 256 + 8 * hi;
        f32x4 acc = {};
#pragma unroll
        for (int ks = 0; ks < 8; ks++) {
            float4 f0 = *(const float4*)(er + ks * 32);
            float4 f1 = *(const float4*)(er + ks * 32 + 4);
            bf16x8 Bf = pack8(f0, f1);
            acc = mfma16(Asc[ks], Bf, acc);
        }
        int bloc = rowloc / 9;
        float s[4];
        float mx = -1.0e30f;
#pragma unroll
        for (int r = 0; r < 4; r++) {
            int m = hi * 4 + r;
            s[r] = acc[r] + sU[bloc][m];
            if (m < 9) mx = fmaxf(mx, s[r]);
        }
        mx = fmaxf(mx, __shfl_xor(mx, 16));
        mx = fmaxf(mx, __shfl_xor(mx, 32));
        float ex[4], sm = 0.f;
#pragma unroll
        for (int r = 0; r < 4; r++) {
            int m = hi * 4 + r;
            ex[r] = (m < 9) ? __expf(s[r] - mx) : 0.f;
            sm += ex[r];
        }
        sm += __shfl_xor(sm, 16);
        sm += __shfl_xor(sm, 32);
        float inv = 1.f / sm;
#pragma unroll
        for (int r = 0; r < 4; r++) {
            int m = hi * 4 + r;
            if (m < 9) atomicAdd(&sW[bloc][m], ex[r] * inv);
        }
    }
    __syncthreads();

    // ---- phase 3: wave-per-row, fully coalesced (1KB/instr enc reads) ----
    for (int i = 0; i < 16; i++) {
        int bl = w * 16 + i;
        size_t b = (size_t)(B0 + bl);
        float wsv[9];
#pragma unroll
        for (int m = 0; m < 9; m++) wsv[m] = sW[bl][m];
        const float* encR = enc + b * (9 * 256) + 4 * lane;
        float c0 = 0.f, c1 = 0.f, c2 = 0.f, c3 = 0.f;
#pragma unroll
        for (int m = 0; m < 9; m++) {
            float4 e4 = *(const float4*)(encR + m * 256);
            c0 += wsv[m] * e4.x; c1 += wsv[m] * e4.y;
            c2 += wsv[m] * e4.z; c3 += wsv[m] * e4.w;
        }
        ushort4 cb; cb.x = f2bf(c0); cb.y = f2bf(c1); cb.z = f2bf(c2); cb.w = f2bf(c3);
        *(ushort4*)(xcat + b * 768 + 512 + 4 * lane) = cb;
        float4 h4 = *(const float4*)(hidden + b * 256 + 4 * lane);
        ushort4 hb; hb.x = f2bf(h4.x); hb.y = f2bf(h4.y); hb.z = f2bf(h4.z); hb.w = f2bf(h4.w);
        *(ushort4*)(xh + b * 768 + 512 + 4 * lane) = hb;
        int word = dw[b];
        const float* er2 = emb + (size_t)word * 512 + 8 * lane;
        float4 e0 = *(const float4*)er2;
        float4 e1 = *(const float4*)(er2 + 4);
        ushort4 w0; w0.x = f2bf(e0.x); w0.y = f2bf(e0.y); w0.z = f2bf(e0.z); w0.w = f2bf(e0.w);
        ushort4 w1; w1.x = f2bf(e1.x); w1.y = f2bf(e1.y); w1.z = f2bf(e1.z); w1.w = f2bf(e1.w);
        *(ushort4*)(xcat + b * 768 + 8 * lane) = w0;
        *(ushort4*)(xcat + b * 768 + 8 * lane + 4) = w1;
    }
}

// ---------------- K2: x = relu(xcat @ comb_W^T + comb_b) -> xh[:,0:512] ----------------
// grid 1024 = 8 xcd x 32 bx x 4 by; tile 128M x 128N; BK=64 dbuf (2x16KB), M-rep 2.
__global__ __launch_bounds__(256, 4) void k_combine(
    const unsigned short* __restrict__ xcat, const unsigned short* __restrict__ cwb,
    const float* __restrict__ comb_b, unsigned short* __restrict__ xh) {
    __shared__ __align__(16) char smem[32768];
    int wgid = blockIdx.x;
    int xcd = wgid & 7, slot = wgid >> 3;
    int bx = xcd * 32 + (slot & 31), by = slot >> 5;     // bx<256, by<4
    int tid = threadIdx.x, w = tid >> 6, lane = tid & 63;
    int lo = lane & 15, hi = lane >> 4;
    int bm0 = bx * 128, n0 = by * 128;
    const __bf16* A = (const __bf16*)xcat;
    const char* gb = (const char*)cwb + (size_t)by * 12 * 16384;
    size_t ar = (size_t)(bm0 + w * 32 + lo) * 768 + 8 * hi;
    f32x4 acc[2][8] = {};
    bf16x8 Afb[2][2][2];
#pragma unroll
    for (int mf = 0; mf < 2; mf++)
#pragma unroll
        for (int ks = 0; ks < 2; ks++)
            Afb[0][mf][ks] = *(const bf16x8*)(A + ar + mf * 16 * 768 + ks * 32);
    for (int it = 0; it < 4; it++) {
        int uo = (w * 4 + it) << 10;
        gload16(gb + uo + lane * 16, smem + uo);
    }
    __syncthreads();
#pragma unroll
    for (int c = 0; c < 12; c++) {
        int cur = c & 1;
        if (c < 11) {
            const char* gc = gb + (size_t)(c + 1) * 16384;
            char* lb = smem + (cur ^ 1) * 16384;
            for (int it = 0; it < 4; it++) {
                int uo = (w * 4 + it) << 10;
                gload16(gc + uo + lane * 16, lb + uo);
            }
#pragma unroll
            for (int mf = 0; mf < 2; mf++)
#pragma unroll
                for (int ks = 0; ks < 2; ks++)
                    Afb[cur ^ 1][mf][ks] = *(const bf16x8*)(A + ar + mf * 16 * 768 + (c + 1) * 64 + ks * 32);
        }
        const char* cb = smem + cur * 16384;
#pragma unroll
        for (int ks = 0; ks < 2; ks++)
#pragma unroll
            for (int nf = 0; nf < 8; nf++) {
                int row = nf * 16 + lo;
                bf16x8 bfr = *(const bf16x8*)(cb + row * 128 + (((ks * 4 + hi) ^ (lo & 7)) << 4));
                acc[0][nf] = mfma16(Afb[cur][0][ks], bfr, acc[0][nf]);
                acc[1][nf] = mfma16(Afb[cur][1][ks], bfr, acc[1][nf]);
            }
        __syncthreads();
    }
#pragma unroll
    for (int mf = 0; mf < 2; mf++)
#pragma unroll
        for (int nf = 0; nf < 8; nf++) {
            int col = n0 + nf * 16 + lo;
            float cb = comb_b[col];
#pragma unroll
            for (int r = 0; r < 4; r++) {
                int row = bm0 + w * 32 + mf * 16 + hi * 4 + r;
                xh[(size_t)row * 768 + col] = f2bf(fmaxf(acc[mf][nf][r] + cb, 0.f));
            }
        }
}

// ---------------- K3: GRU gates GEMM (interleaved wg2) + in-register epilogue ----------------
// grid 2048 = 8 xcd x 32 bx x 8 by; tile 128M x 128N (32h x 4gates); BK=64 dbuf, M-rep 2.
__global__ __launch_bounds__(256, 4) void k_gru(
    const unsigned short* __restrict__ xh, const unsigned short* __restrict__ wg2,
    const float* __restrict__ bg, const float* __restrict__ hidden,
    float* __restrict__ hnew_out, unsigned short* __restrict__ hnb) {
    __shared__ __align__(16) char smem[32768];
    int wgid = blockIdx.x;
    int xcd = wgid & 7, slot = wgid >> 3;
    int bx = xcd * 32 + (slot & 31), by = slot >> 5;     // bx<256, by<8
    int tid = threadIdx.x, w = tid >> 6, lane = tid & 63;
    int lo = lane & 15, hi = lane >> 4;
    int bm0 = bx * 128;
    int h00 = by * 32;
    const __bf16* A = (const __bf16*)xh;
    const char* gb = (const char*)wg2 + (size_t)by * 12 * 16384;
    size_t ar = (size_t)(bm0 + w * 32 + lo) * 768 + 8 * hi;
    f32x4 acc[2][8] = {};
    bf16x8 Afb[2][2][2];
#pragma unroll
    for (int mf = 0; mf < 2; mf++)
#pragma unroll
        for (int ks = 0; ks < 2; ks++)
            Afb[0][mf][ks] = *(const bf16x8*)(A + ar + mf * 16 * 768 + ks * 32);
    for (int it = 0; it < 4; it++) {
        int uo = (w * 4 + it) << 10;
        gload16(gb + uo + lane * 16, smem + uo);
    }
    __syncthreads();
#pragma unroll
    for (int c = 0; c < 12; c++) {
        int cur = c & 1;
        if (c < 11) {
            const char* gc = gb + (size_t)(c + 1) * 16384;
            char* lb = smem + (cur ^ 1) * 16384;
            for (int it = 0; it < 4; it++) {
                int uo = (w * 4 + it) << 10;
                gload16(gc + uo + lane * 16, lb + uo);
            }
#pragma unroll
            for (int mf = 0; mf < 2; mf++)
#pragma unroll
                for (int ks = 0; ks < 2; ks++)
                    Afb[cur ^ 1][mf][ks] = *(const bf16x8*)(A + ar + mf * 16 * 768 + (c + 1) * 64 + ks * 32);
        }
        const char* cb = smem + cur * 16384;
#pragma unroll
        for (int ks = 0; ks < 2; ks++)
#pragma unroll
            for (int nf = 0; nf < 8; nf++) {
                int row = nf * 16 + lo;
                bf16x8 bfr = *(const bf16x8*)(cb + row * 128 + (((ks * 4 + hi) ^ (lo & 7)) << 4));
                acc[0][nf] = mfma16(Afb[cur][0][ks], bfr, acc[0][nf]);
                acc[1][nf] = mfma16(Afb[cur][1][ks], bfr, acc[1][nf]);
            }
        __syncthreads();
    }
    // epilogue: acc[mf][hgrp*4 + g] holds gate g for h-col = h00 + hgrp*16 + lo
#pragma unroll
    for (int mf = 0; mf < 2; mf++)
#pragma unroll
        for (int hgrp = 0; hgrp < 2; hgrp++) {
            int col = h00 + hgrp * 16 + lo;
            float br = bg[col], bz = bg[256 + col], bi = bg[512 + col], bh = bg[768 + col];
#pragma unroll
            for (int r = 0; r < 4; r++) {
                int row = bm0 + w * 32 + mf * 16 + hi * 4 + r;
                float rr = 1.f / (1.f + __expf(-(acc[mf][hgrp * 4 + 0][r] + br)));
                float zz = 1.f / (1.f + __expf(-(acc[mf][hgrp * 4 + 1][r] + bz)));
                float nn = tanhf(acc[mf][hgrp * 4 + 2][r] + bi + rr * (acc[mf][hgrp * 4 + 3][r] + bh));
                float hp = hidden[(size_t)row * 256 + col];
                float hn = zz * (hp - nn) + nn;
                hnew_out[(size_t)row * 256 + col] = hn;
                hnb[(size_t)row * 256 + col] = f2bf(hn);
            }
        }
}

// ---------------- K4: vocab GEMM (once): bf16 logits into out rows + psum ----------------
// grid 8192 = 8 xcd x 32 bx x 32 by; tile 128M x 128N; K=256 = 4 BK=64 dbuf chunks, M-rep 2.
__global__ __launch_bounds__(256, 4) void k_logit(
    const unsigned short* __restrict__ hnb, const unsigned short* __restrict__ owb,
    const float* __restrict__ obp, unsigned short* __restrict__ lgt,
    float* __restrict__ psum) {
    __shared__ __align__(16) char smem[34816];   // dbuf 2x16KB; T [128][136] ushort = 34816B
    int wgid = blockIdx.x;
    int xcd = wgid & 7, slot = wgid >> 3;
    int bx = xcd * 32 + (slot & 31), by = slot >> 5;     // bx<256, by<32
    int tid = threadIdx.x, w = tid >> 6, lane = tid & 63;
    int lo = lane & 15, hi = lane >> 4;
    int bm0 = bx * 128, n0 = by * 128;
    const __bf16* A = (const __bf16*)hnb;
    const char* gb = (const char*)owb + (size_t)by * 4 * 16384;
    size_t ar = (size_t)(bm0 + w * 32 + lo) * 256 + 8 * hi;
    f32x4 acc[2][8] = {};
    bf16x8 Afb[2][2][2];
#pragma unroll
    for (int mf = 0; mf < 2; mf++)
#pragma unroll
        for (int ks = 0; ks < 2; ks++)
            Afb[0][mf][ks] = *(const bf16x8*)(A + ar + mf * 16 * 256 + ks * 32);
    for (int it = 0; it < 4; it++) {
        int uo = (w * 4 + it) << 10;
        gload16(gb + uo + lane * 16, smem + uo);
    }
    __syncthreads();
#pragma unroll
    for (int c = 0; c < 4; c++) {
        int cur = c & 1;
        if (c < 3) {
            const char* gc = gb + (size_t)(c + 1) * 16384;
            char* lb = smem + (cur ^ 1) * 16384;
            for (int it = 0; it < 4; it++) {
                int uo = (w * 4 + it) << 10;
                gload16(gc + uo + lane * 16, lb + uo);
            }
#pragma unroll
            for (int mf = 0; mf < 2; mf++)
#pragma unroll
                for (int ks = 0; ks < 2; ks++)
                    Afb[cur ^ 1][mf][ks] = *(const bf16x8*)(A + ar + mf * 16 * 256 + (c + 1) * 64 + ks * 32);
        }
        const char* cb = smem + cur * 16384;
#pragma unroll
        for (int ks = 0; ks < 2; ks++)
#pragma unroll
            for (int nf = 0; nf < 8; nf++) {
                int row = nf * 16 + lo;
                bf16x8 bfr = *(const bf16x8*)(cb + row * 128 + (((ks * 4 + hi) ^ (lo & 7)) << 4));
                acc[0][nf] = mfma16(Afb[cur][0][ks], bfr, acc[0][nf]);
                acc[1][nf] = mfma16(Afb[cur][1][ks], bfr, acc[1][nf]);
            }
        __syncthreads();
    }

    unsigned short* T = (unsigned short*)smem;   // [128][136]
    float se[2][4] = {};
#pragma unroll
    for (int mf = 0; mf < 2; mf++)
#pragma unroll
        for (int nf = 0; nf < 8; nf++) {
            int col = n0 + nf * 16 + lo;
            float ob = obp[col];
#pragma unroll
            for (int r = 0; r < 4; r++) {
                float lg = acc[mf][nf][r] + ob;
                se[mf][r] += __expf(lg);
                T[(w * 32 + mf * 16 + hi * 4 + r) * 136 + nf * 16 + lo] = f2bf(lg);
            }
        }
#pragma unroll
    for (int mf = 0; mf < 2; mf++)
#pragma unroll
        for (int r = 0; r < 4; r++) {
            float v = se[mf][r];
            v += __shfl_xor(v, 1); v += __shfl_xor(v, 2);
            v += __shfl_xor(v, 4); v += __shfl_xor(v, 8);
            se[mf][r] = v;
        }
    if (lo == 0) {
#pragma unroll
        for (int mf = 0; mf < 2; mf++)
#pragma unroll
            for (int r = 0; r < 4; r++)
                psum[(size_t)by * BATCH_ + bm0 + w * 32 + mf * 16 + hi * 4 + r] = se[mf][r];
    }
    __syncthreads();
#pragma unroll
    for (int it = 0; it < 8; it++) {
        int t = it * 256 + tid;
        int row = t >> 4, ch = t & 15;
        ushort4 a = *(ushort4*)(T + row * 136 + ch * 8);
        ushort4 b = *(ushort4*)(T + row * 136 + ch * 8 + 4);
        size_t base = (size_t)(bm0 + row) * LGT_STRIDE + n0 + ch * 8;
        *(ushort4*)(lgt + base) = a;
        *(ushort4*)(lgt + base + 4) = b;
    }
}

// ---------------- K5: fused lse + streaming out[b][v] = bf16logit - lse (in-place) ----------------
__global__ __launch_bounds__(256) void k_out2(
    const float* __restrict__ psum, float* __restrict__ out) {
    __shared__ float sl;
    int b = blockIdx.x, tid = threadIdx.x;
    const unsigned short* rowp = (const unsigned short*)(out + (size_t)b * VOC);
    ushort4 a0 = *(const ushort4*)(rowp + tid * 8);
    ushort4 b0 = *(const ushort4*)(rowp + tid * 8 + 4);
    ushort4 a1 = *(const ushort4*)(rowp + 2048 + tid * 8);
    ushort4 b1 = *(const ushort4*)(rowp + 2048 + tid * 8 + 4);
    if (tid < 32) {
        float v = psum[(size_t)tid * BATCH_ + b];
        v += __shfl_xor(v, 1); v += __shfl_xor(v, 2); v += __shfl_xor(v, 4);
        v += __shfl_xor(v, 8); v += __shfl_xor(v, 16);
        if (tid == 0) sl = __logf(v);
    }
    __syncthreads();      // lse ready + all reads done before in-place overwrite
    float l = sl;
    float* orow = out + (size_t)b * VOC;
    int v0 = tid * 8;
    {
        float2 p;
        p.x = bf2f(a0.x) - l; p.y = bf2f(a0.y) - l; *(float2*)(orow + v0) = p;
        p.x = bf2f(a0.z) - l; p.y = bf2f(a0.w) - l; *(float2*)(orow + v0 + 2) = p;
        p.x = bf2f(b0.x) - l; p.y = bf2f(b0.y) - l; *(float2*)(orow + v0 + 4) = p;
        p.x = bf2f(b0.z) - l; p.y = bf2f(b0.w) - l; *(float2*)(orow + v0 + 6) = p;
    }
    int v1 = 2048 + tid * 8;
    {
        float2 p;
        p.x = bf2f(a1.x) - l; p.y = bf2f(a1.y) - l;
        if (v1 + 1 < VOC) *(float2*)(orow + v1) = p;
        p.x = bf2f(a1.z) - l; p.y = bf2f(a1.w) - l;
        if (v1 + 3 < VOC) *(float2*)(orow + v1 + 2) = p;
        p.x = bf2f(b1.x) - l; p.y = bf2f(b1.y) - l;
        if (v1 + 5 < VOC) *(float2*)(orow + v1 + 4) = p;
        p.x = bf2f(b1.z) - l; p.y = bf2f(b1.w) - l;
        if (v1 + 7 < VOC) *(float2*)(orow + v1 + 6) = p;
    }
}

extern "C" void kernel_launch(void* const* d_in, const int* in_sizes, int n_in,
                              void* d_out, int out_size, void* d_ws, size_t ws_size,
                              hipStream_t stream) {
    const int*   dw      = (const int*)d_in[0];
    const float* hidden  = (const float*)d_in[1];
    const float* enc     = (const float*)d_in[2];
    const float* emb     = (const float*)d_in[3];
    const float* aW      = (const float*)d_in[4];
    const float* ab      = (const float*)d_in[5];
    const float* comb_W  = (const float*)d_in[6];
    const float* comb_b  = (const float*)d_in[7];
    const float* W_ih    = (const float*)d_in[8];
    const float* b_ih    = (const float*)d_in[9];
    const float* W_hh    = (const float*)d_in[10];
    const float* b_hh    = (const float*)d_in[11];
    const float* out_W   = (const float*)d_in[12];
    const float* out_b   = (const float*)d_in[13];

    float* out = (float*)d_out;
    float* hnew_out = out + (size_t)BATCH_ * VOC;

    unsigned short* xcat = (unsigned short*)d_ws;
    unsigned short* xh   = xcat + (size_t)BATCH_ * 768;
    unsigned short* hnb  = xh + (size_t)BATCH_ * 768;
    float* psum          = (float*)(hnb + (size_t)BATCH_ * 256);   // 32 * BATCH floats
    float* obp           = psum + (size_t)32 * BATCH_;             // 4096 floats
    unsigned short* cwb  = (unsigned short*)(obp + 4096);
    unsigned short* wg2  = cwb + 512 * 768;
    unsigned short* owb  = wg2 + 1024 * 768;
    float* bg            = (float*)(owb + 4096 * 256);

    k_prep<<<4096, 256, 0, stream>>>(comb_W, W_ih, W_hh, out_W, b_ih, b_hh, out_b,
                                     cwb, wg2, owb, bg, obp);
    k_attn<<<BATCH_ / 64, 256, 0, stream>>>(dw, hidden, enc, emb, aW, ab, xcat, xh);
    k_combine<<<1024, 256, 0, stream>>>(xcat, cwb, comb_b, xh);
    k_gru<<<2048, 256, 0, stream>>>(xh, wg2, bg, hidden, hnew_out, hnb);
    k_logit<<<8192, 256, 0, stream>>>(hnb, owb, obp, (unsigned short*)out, psum);
    k_out2<<<BATCH_, 256, 0, stream>>>(psum, out);
}

// Round 13
// 719.470 us; speedup vs baseline: 1.3677x; 1.0256x over previous
//
#include <hip/hip_runtime.h>

typedef __bf16 bf16x8 __attribute__((ext_vector_type(8)));
typedef unsigned short u16x8 __attribute__((ext_vector_type(8)));
typedef float  f32x4  __attribute__((ext_vector_type(4)));

#define BATCH_ 32768
#define VOC 4094
#define LGT_STRIDE 8188   // ushorts per out row (4094 f32)

__device__ inline unsigned short f2bf(float f) {
    unsigned int u = __builtin_bit_cast(unsigned int, f);
    unsigned int r = u + 0x7FFFu + ((u >> 16) & 1u);
    return (unsigned short)(r >> 16);
}
__device__ inline float bf2f(unsigned short u) {
    unsigned int v = ((unsigned int)u) << 16;
    return __builtin_bit_cast(float, v);
}
__device__ inline f32x4 mfma16(bf16x8 a, bf16x8 b, f32x4 c) {
    return __builtin_amdgcn_mfma_f32_16x16x32_bf16(a, b, c, 0, 0, 0);
}
__device__ inline void gload16(const void* g, void* l) {
    __builtin_amdgcn_global_load_lds(
        (const __attribute__((address_space(1))) void*)(g),
        (__attribute__((address_space(3))) void*)(l),
        16, 0, 0);
}
__device__ inline bf16x8 pack8(float4 a, float4 b) {
    u16x8 u;
    u[0] = f2bf(a.x); u[1] = f2bf(a.y); u[2] = f2bf(a.z); u[3] = f2bf(a.w);
    u[4] = f2bf(b.x); u[5] = f2bf(b.y); u[6] = f2bf(b.z); u[7] = f2bf(b.w);
    return __builtin_bit_cast(bf16x8, u);
}

// ---------------- K0: weight prep -> pre-swizzled 16KB chunk images (BK=64) ----------------
__global__ __launch_bounds__(256) void k_prep(
    const float* __restrict__ comb_W, const float* __restrict__ W_ih,
    const float* __restrict__ W_hh, const float* __restrict__ out_W,
    const float* __restrict__ b_ih, const float* __restrict__ b_hh,
    const float* __restrict__ out_b,
    unsigned short* __restrict__ cwb, unsigned short* __restrict__ wg2,
    unsigned short* __restrict__ owb, float* __restrict__ bg,
    float* __restrict__ obp) {
    int i = blockIdx.x * 256 + threadIdx.x;      // grid covers 1,048,576
    if (i < 512 * 768) {
        int n = i / 768, k = i - n * 768;
        int by = n >> 7, r = n & 127, kc = k >> 6, kl = k & 63;
        int dst = (by * 12 + kc) * 8192 + r * 64 + (((kl >> 3) ^ (r & 7)) << 3) + (kl & 7);
        cwb[dst] = f2bf(comb_W[i]);
    }
    if (i < 1024 * 768) {
        int row = i / 768, k = i - row * 768;
        int hgrp = row >> 6, g = (row >> 4) & 3, hl = row & 15;
        int h = hgrp * 16 + hl;
        float v;
        if (g == 0) v = (k < 512) ? W_ih[(size_t)h * 512 + k] : W_hh[(size_t)h * 256 + (k - 512)];
        else if (g == 1) v = (k < 512) ? W_ih[(size_t)(256 + h) * 512 + k] : W_hh[(size_t)(256 + h) * 256 + (k - 512)];
        else if (g == 2) v = (k < 512) ? W_ih[(size_t)(512 + h) * 512 + k] : 0.f;
        else v = (k < 512) ? 0.f : W_hh[(size_t)(512 + h) * 256 + (k - 512)];
        int by = row >> 7, r = row & 127, kc = k >> 6, kl = k & 63;
        int dst = (by * 12 + kc) * 8192 + r * 64 + (((kl >> 3) ^ (r & 7)) << 3) + (kl & 7);
        wg2[dst] = f2bf(v);
    }
    if (i < 4096 * 256) {
        int n = i >> 8, k = i & 255;
        int by = n >> 7, r = n & 127, kc = k >> 6, kl = k & 63;
        int dst = (by * 4 + kc) * 8192 + r * 64 + (((kl >> 3) ^ (r & 7)) << 3) + (kl & 7);
        owb[dst] = (n < VOC) ? f2bf(out_W[i]) : (unsigned short)0;
    }
    if (i < 1024) {
        float v = (i < 512) ? (b_ih[i] + b_hh[i]) : ((i < 768) ? b_ih[i] : b_hh[i - 256]);
        bg[i] = v;
    }
    if (i < 4096) obp[i] = (i < VOC) ? out_b[i] : -1.0e30f;
}

// ---------------- K1: attention (32 rows / block, 4 waves, 1024 blocks) ----------------
// phase1: u[b][m] = h@aW2^T + ab   (MFMA, waves 0-1)
// phase2: 18 tiles round-robin over 4 waves; softmax over m (2 shfl); wsum via LDS atomic
// phase3: wave-per-row coalesced: c = sum_m wsum*enc; write c,h (bf16) + emb gather
__global__ __launch_bounds__(256) void k_attn(
    const int* __restrict__ dw, const float* __restrict__ hidden,
    const float* __restrict__ enc, const float* __restrict__ emb,
    const float* __restrict__ aW, const float* __restrict__ ab,
    unsigned short* __restrict__ xcat, unsigned short* __restrict__ xh) {
    __shared__ __align__(16) unsigned short sA1[16 * 264];  // aW[:, :256] bf16, rows>=9 zero
    __shared__ __align__(16) unsigned short sA2[16 * 264];  // aW[:, 256:] bf16
    __shared__ float sU[32][17];
    __shared__ float sW[32][17];
    __shared__ float sAB[16];
    int tid = threadIdx.x, w = tid >> 6, lane = tid & 63;
    int lo = lane & 15, hi = lane >> 4;
    int B0 = blockIdx.x * 32;

    for (int i = tid; i < 16 * 256; i += 256) {
        int m = i >> 8, k = i & 255;
        float v1 = (m < 9) ? aW[m * 512 + k] : 0.f;
        float v2 = (m < 9) ? aW[m * 512 + 256 + k] : 0.f;
        sA1[m * 264 + k] = f2bf(v1);
        sA2[m * 264 + k] = f2bf(v2);
    }
    if (tid < 16) sAB[tid] = (tid < 9) ? ab[tid] : 0.f;
    if (tid < 32) {
#pragma unroll
        for (int m = 0; m < 16; m++) sW[tid][m] = 0.f;
    }
    __syncthreads();

    // ---- phase 1: u tiles (waves 0,1; b = B0 + w*16 + lo) ----
    if (w < 2) {
        const float* hrow = hidden + (size_t)(B0 + w * 16 + lo) * 256 + 8 * hi;
        f32x4 uacc = {};
#pragma unroll
        for (int ks = 0; ks < 8; ks++) {
            float4 f0 = *(const float4*)(hrow + ks * 32);
            float4 f1 = *(const float4*)(hrow + ks * 32 + 4);
            bf16x8 Bf = pack8(f0, f1);
            bf16x8 Af = *(const bf16x8*)(sA2 + lo * 264 + ks * 32 + 8 * hi);
            uacc = mfma16(Af, Bf, uacc);
        }
#pragma unroll
        for (int r = 0; r < 4; r++) {
            int m = hi * 4 + r;
            sU[w * 16 + lo][m] = uacc[r] + sAB[m];
        }
    }
    __syncthreads();

    // ---- phase 2: 18 tiles (288 = 32b x 9l rows), round-robin t = w + 4*t8 ----
    bf16x8 Asc[8];
#pragma unroll
    for (int ks = 0; ks < 8; ks++)
        Asc[ks] = *(const bf16x8*)(sA1 + lo * 264 + ks * 32 + 8 * hi);
    const float* encF = enc + (size_t)B0 * 9 * 256;
#pragma unroll
    for (int t8 = 0; t8 < 5; t8++) {
        int t = w + t8 * 4;
        if (t < 18) {
            int rowloc = t * 16 + lo;              // flat (b,l) within block
            const float* er = encF + (size_t)rowloc * 256 + 8 * hi;
            f32x4 acc = {};
#pragma unroll
            for (int ks = 0; ks < 8; ks++) {
                float4 f0 = *(const float4*)(er + ks * 32);
                float4 f1 = *(const float4*)(er + ks * 32 + 4);
                bf16x8 Bf = pack8(f0, f1);
                acc = mfma16(Asc[ks], Bf, acc);
            }
            int bloc = rowloc / 9;
            float s[4];
            float mx = -1.0e30f;
#pragma unroll
            for (int r = 0; r < 4; r++) {
                int m = hi * 4 + r;
                s[r] = acc[r] + sU[bloc][m];
                if (m < 9) mx = fmaxf(mx, s[r]);
            }
            mx = fmaxf(mx, __shfl_xor(mx, 16));
            mx = fmaxf(mx, __shfl_xor(mx, 32));
            float ex[4], sm = 0.f;
#pragma unroll
            for (int r = 0; r < 4; r++) {
                int m = hi * 4 + r;
                ex[r] = (m < 9) ? __expf(s[r] - mx) : 0.f;
                sm += ex[r];
            }
            sm += __shfl_xor(sm, 16);
            sm += __shfl_xor(sm, 32);
            float inv = 1.f / sm;
#pragma unroll
            for (int r = 0; r < 4; r++) {
                int m = hi * 4 + r;
                if (m < 9) atomicAdd(&sW[bloc][m], ex[r] * inv);
            }
        }
    }
    __syncthreads();

    // ---- phase 3: wave-per-row, fully coalesced (1KB/instr enc reads), 8 rows/wave ----
    for (int i = 0; i < 8; i++) {
        int bl = w * 8 + i;
        size_t b = (size_t)(B0 + bl);
        float wsv[9];
#pragma unroll
        for (int m = 0; m < 9; m++) wsv[m] = sW[bl][m];
        const float* encR = enc + b * (9 * 256) + 4 * lane;
        float c0 = 0.f, c1 = 0.f, c2 = 0.f, c3 = 0.f;
#pragma unroll
        for (int m = 0; m < 9; m++) {
            float4 e4 = *(const float4*)(encR + m * 256);
            c0 += wsv[m] * e4.x; c1 += wsv[m] * e4.y;
            c2 += wsv[m] * e4.z; c3 += wsv[m] * e4.w;
        }
        ushort4 cb; cb.x = f2bf(c0); cb.y = f2bf(c1); cb.z = f2bf(c2); cb.w = f2bf(c3);
        *(ushort4*)(xcat + b * 768 + 512 + 4 * lane) = cb;
        float4 h4 = *(const float4*)(hidden + b * 256 + 4 * lane);
        ushort4 hb; hb.x = f2bf(h4.x); hb.y = f2bf(h4.y); hb.z = f2bf(h4.z); hb.w = f2bf(h4.w);
        *(ushort4*)(xh + b * 768 + 512 + 4 * lane) = hb;
        int word = dw[b];
        const float* er2 = emb + (size_t)word * 512 + 8 * lane;
        float4 e0 = *(const float4*)er2;
        float4 e1 = *(const float4*)(er2 + 4);
        ushort4 w0; w0.x = f2bf(e0.x); w0.y = f2bf(e0.y); w0.z = f2bf(e0.z); w0.w = f2bf(e0.w);
        ushort4 w1; w1.x = f2bf(e1.x); w1.y = f2bf(e1.y); w1.z = f2bf(e1.z); w1.w = f2bf(e1.w);
        *(ushort4*)(xcat + b * 768 + 8 * lane) = w0;
        *(ushort4*)(xcat + b * 768 + 8 * lane + 4) = w1;
    }
}

// ---------------- K2: x = relu(xcat @ comb_W^T + comb_b) -> xh[:,0:512] ----------------
// grid 1024 = 8 xcd x 32 bx x 4 by; tile 128M x 128N; BK=64 dbuf (2x16KB), M-rep 2.
__global__ __launch_bounds__(256, 4) void k_combine(
    const unsigned short* __restrict__ xcat, const unsigned short* __restrict__ cwb,
    const float* __restrict__ comb_b, unsigned short* __restrict__ xh) {
    __shared__ __align__(16) char smem[32768];
    int wgid = blockIdx.x;
    int xcd = wgid & 7, slot = wgid >> 3;
    int bx = xcd * 32 + (slot & 31), by = slot >> 5;     // bx<256, by<4
    int tid = threadIdx.x, w = tid >> 6, lane = tid & 63;
    int lo = lane & 15, hi = lane >> 4;
    int bm0 = bx * 128, n0 = by * 128;
    const __bf16* A = (const __bf16*)xcat;
    const char* gb = (const char*)cwb + (size_t)by * 12 * 16384;
    size_t ar = (size_t)(bm0 + w * 32 + lo) * 768 + 8 * hi;
    f32x4 acc[2][8] = {};
    bf16x8 Afb[2][2][2];
#pragma unroll
    for (int mf = 0; mf < 2; mf++)
#pragma unroll
        for (int ks = 0; ks < 2; ks++)
            Afb[0][mf][ks] = *(const bf16x8*)(A + ar + mf * 16 * 768 + ks * 32);
    for (int it = 0; it < 4; it++) {
        int uo = (w * 4 + it) << 10;
        gload16(gb + uo + lane * 16, smem + uo);
    }
    __syncthreads();
#pragma unroll
    for (int c = 0; c < 12; c++) {
        int cur = c & 1;
        if (c < 11) {
            const char* gc = gb + (size_t)(c + 1) * 16384;
            char* lb = smem + (cur ^ 1) * 16384;
            for (int it = 0; it < 4; it++) {
                int uo = (w * 4 + it) << 10;
                gload16(gc + uo + lane * 16, lb + uo);
            }
#pragma unroll
            for (int mf = 0; mf < 2; mf++)
#pragma unroll
                for (int ks = 0; ks < 2; ks++)
                    Afb[cur ^ 1][mf][ks] = *(const bf16x8*)(A + ar + mf * 16 * 768 + (c + 1) * 64 + ks * 32);
        }
        const char* cb = smem + cur * 16384;
#pragma unroll
        for (int ks = 0; ks < 2; ks++)
#pragma unroll
            for (int nf = 0; nf < 8; nf++) {
                int row = nf * 16 + lo;
                bf16x8 bfr = *(const bf16x8*)(cb + row * 128 + (((ks * 4 + hi) ^ (lo & 7)) << 4));
                acc[0][nf] = mfma16(Afb[cur][0][ks], bfr, acc[0][nf]);
                acc[1][nf] = mfma16(Afb[cur][1][ks], bfr, acc[1][nf]);
            }
        __syncthreads();
    }
#pragma unroll
    for (int mf = 0; mf < 2; mf++)
#pragma unroll
        for (int nf = 0; nf < 8; nf++) {
            int col = n0 + nf * 16 + lo;
            float cb = comb_b[col];
#pragma unroll
            for (int r = 0; r < 4; r++) {
                int row = bm0 + w * 32 + mf * 16 + hi * 4 + r;
                xh[(size_t)row * 768 + col] = f2bf(fmaxf(acc[mf][nf][r] + cb, 0.f));
            }
        }
}

// ---------------- K3: GRU gates GEMM (interleaved wg2) + in-register epilogue ----------------
// grid 2048 = 8 xcd x 32 bx x 8 by; tile 128M x 128N (32h x 4gates); BK=64 dbuf, M-rep 2.
__global__ __launch_bounds__(256, 4) void k_gru(
    const unsigned short* __restrict__ xh, const unsigned short* __restrict__ wg2,
    const float* __restrict__ bg, const float* __restrict__ hidden,
    float* __restrict__ hnew_out, unsigned short* __restrict__ hnb) {
    __shared__ __align__(16) char smem[32768];
    int wgid = blockIdx.x;
    int xcd = wgid & 7, slot = wgid >> 3;
    int bx = xcd * 32 + (slot & 31), by = slot >> 5;     // bx<256, by<8
    int tid = threadIdx.x, w = tid >> 6, lane = tid & 63;
    int lo = lane & 15, hi = lane >> 4;
    int bm0 = bx * 128;
    int h00 = by * 32;
    const __bf16* A = (const __bf16*)xh;
    const char* gb = (const char*)wg2 + (size_t)by * 12 * 16384;
    size_t ar = (size_t)(bm0 + w * 32 + lo) * 768 + 8 * hi;
    f32x4 acc[2][8] = {};
    bf16x8 Afb[2][2][2];
#pragma unroll
    for (int mf = 0; mf < 2; mf++)
#pragma unroll
        for (int ks = 0; ks < 2; ks++)
            Afb[0][mf][ks] = *(const bf16x8*)(A + ar + mf * 16 * 768 + ks * 32);
    for (int it = 0; it < 4; it++) {
        int uo = (w * 4 + it) << 10;
        gload16(gb + uo + lane * 16, smem + uo);
    }
    __syncthreads();
#pragma unroll
    for (int c = 0; c < 12; c++) {
        int cur = c & 1;
        if (c < 11) {
            const char* gc = gb + (size_t)(c + 1) * 16384;
            char* lb = smem + (cur ^ 1) * 16384;
            for (int it = 0; it < 4; it++) {
                int uo = (w * 4 + it) << 10;
                gload16(gc + uo + lane * 16, lb + uo);
            }
#pragma unroll
            for (int mf = 0; mf < 2; mf++)
#pragma unroll
                for (int ks = 0; ks < 2; ks++)
                    Afb[cur ^ 1][mf][ks] = *(const bf16x8*)(A + ar + mf * 16 * 768 + (c + 1) * 64 + ks * 32);
        }
        const char* cb = smem + cur * 16384;
#pragma unroll
        for (int ks = 0; ks < 2; ks++)
#pragma unroll
            for (int nf = 0; nf < 8; nf++) {
                int row = nf * 16 + lo;
                bf16x8 bfr = *(const bf16x8*)(cb + row * 128 + (((ks * 4 + hi) ^ (lo & 7)) << 4));
                acc[0][nf] = mfma16(Afb[cur][0][ks], bfr, acc[0][nf]);
                acc[1][nf] = mfma16(Afb[cur][1][ks], bfr, acc[1][nf]);
            }
        __syncthreads();
    }
    // epilogue: acc[mf][hgrp*4 + g] holds gate g for h-col = h00 + hgrp*16 + lo
#pragma unroll
    for (int mf = 0; mf < 2; mf++)
#pragma unroll
        for (int hgrp = 0; hgrp < 2; hgrp++) {
            int col = h00 + hgrp * 16 + lo;
            float br = bg[col], bz = bg[256 + col], bi = bg[512 + col], bh = bg[768 + col];
#pragma unroll
            for (int r = 0; r < 4; r++) {
                int row = bm0 + w * 32 + mf * 16 + hi * 4 + r;
                float rr = 1.f / (1.f + __expf(-(acc[mf][hgrp * 4 + 0][r] + br)));
                float zz = 1.f / (1.f + __expf(-(acc[mf][hgrp * 4 + 1][r] + bz)));
                float nn = tanhf(acc[mf][hgrp * 4 + 2][r] + bi + rr * (acc[mf][hgrp * 4 + 3][r] + bh));
                float hp = hidden[(size_t)row * 256 + col];
                float hn = zz * (hp - nn) + nn;
                hnew_out[(size_t)row * 256 + col] = hn;
                hnb[(size_t)row * 256 + col] = f2bf(hn);
            }
        }
}

// ---------------- K4: vocab GEMM (once): bf16 logits into out rows + psum ----------------
// grid 8192 = 8 xcd x 32 bx x 32 by; tile 128M x 128N; K=256 = 4 BK=64 dbuf chunks, M-rep 2.
__global__ __launch_bounds__(256, 4) void k_logit(
    const unsigned short* __restrict__ hnb, const unsigned short* __restrict__ owb,
    const float* __restrict__ obp, unsigned short* __restrict__ lgt,
    float* __restrict__ psum) {
    __shared__ __align__(16) char smem[34816];   // dbuf 2x16KB; T [128][136] ushort = 34816B
    int wgid = blockIdx.x;
    int xcd = wgid & 7, slot = wgid >> 3;
    int bx = xcd * 32 + (slot & 31), by = slot >> 5;     // bx<256, by<32
    int tid = threadIdx.x, w = tid >> 6, lane = tid & 63;
    int lo = lane & 15, hi = lane >> 4;
    int bm0 = bx * 128, n0 = by * 128;
    const __bf16* A = (const __bf16*)hnb;
    const char* gb = (const char*)owb + (size_t)by * 4 * 16384;
    size_t ar = (size_t)(bm0 + w * 32 + lo) * 256 + 8 * hi;
    f32x4 acc[2][8] = {};
    bf16x8 Afb[2][2][2];
#pragma unroll
    for (int mf = 0; mf < 2; mf++)
#pragma unroll
        for (int ks = 0; ks < 2; ks++)
            Afb[0][mf][ks] = *(const bf16x8*)(A + ar + mf * 16 * 256 + ks * 32);
    for (int it = 0; it < 4; it++) {
        int uo = (w * 4 + it) << 10;
        gload16(gb + uo + lane * 16, smem + uo);
    }
    __syncthreads();
#pragma unroll
    for (int c = 0; c < 4; c++) {
        int cur = c & 1;
        if (c < 3) {
            const char* gc = gb + (size_t)(c + 1) * 16384;
            char* lb = smem + (cur ^ 1) * 16384;
            for (int it = 0; it < 4; it++) {
                int uo = (w * 4 + it) << 10;
                gload16(gc + uo + lane * 16, lb + uo);
            }
#pragma unroll
            for (int mf = 0; mf < 2; mf++)
#pragma unroll
                for (int ks = 0; ks < 2; ks++)
                    Afb[cur ^ 1][mf][ks] = *(const bf16x8*)(A + ar + mf * 16 * 256 + (c + 1) * 64 + ks * 32);
        }
        const char* cb = smem + cur * 16384;
#pragma unroll
        for (int ks = 0; ks < 2; ks++)
#pragma unroll
            for (int nf = 0; nf < 8; nf++) {
                int row = nf * 16 + lo;
                bf16x8 bfr = *(const bf16x8*)(cb + row * 128 + (((ks * 4 + hi) ^ (lo & 7)) << 4));
                acc[0][nf] = mfma16(Afb[cur][0][ks], bfr, acc[0][nf]);
                acc[1][nf] = mfma16(Afb[cur][1][ks], bfr, acc[1][nf]);
            }
        __syncthreads();
    }

    unsigned short* T = (unsigned short*)smem;   // [128][136]
    float se[2][4] = {};
#pragma unroll
    for (int mf = 0; mf < 2; mf++)
#pragma unroll
        for (int nf = 0; nf < 8; nf++) {
            int col = n0 + nf * 16 + lo;
            float ob = obp[col];
#pragma unroll
            for (int r = 0; r < 4; r++) {
                float lg = acc[mf][nf][r] + ob;
                se[mf][r] += __expf(lg);
                T[(w * 32 + mf * 16 + hi * 4 + r) * 136 + nf * 16 + lo] = f2bf(lg);
            }
        }
#pragma unroll
    for (int mf = 0; mf < 2; mf++)
#pragma unroll
        for (int r = 0; r < 4; r++) {
            float v = se[mf][r];
            v += __shfl_xor(v, 1); v += __shfl_xor(v, 2);
            v += __shfl_xor(v, 4); v += __shfl_xor(v, 8);
            se[mf][r] = v;
        }
    if (lo == 0) {
#pragma unroll
        for (int mf = 0; mf < 2; mf++)
#pragma unroll
            for (int r = 0; r < 4; r++)
                psum[(size_t)by * BATCH_ + bm0 + w * 32 + mf * 16 + hi * 4 + r] = se[mf][r];
    }
    __syncthreads();
#pragma unroll
    for (int it = 0; it < 8; it++) {
        int t = it * 256 + tid;
        int row = t >> 4, ch = t & 15;
        ushort4 a = *(ushort4*)(T + row * 136 + ch * 8);
        ushort4 b = *(ushort4*)(T + row * 136 + ch * 8 + 4);
        size_t base = (size_t)(bm0 + row) * LGT_STRIDE + n0 + ch * 8;
        *(ushort4*)(lgt + base) = a;
        *(ushort4*)(lgt + base + 4) = b;
    }
}

// ---------------- K5: fused lse + streaming out[b][v] = bf16logit - lse (in-place) ----------------
__global__ __launch_bounds__(256) void k_out2(
    const float* __restrict__ psum, float* __restrict__ out) {
    __shared__ float sl;
    int b = blockIdx.x, tid = threadIdx.x;
    const unsigned short* rowp = (const unsigned short*)(out + (size_t)b * VOC);
    ushort4 a0 = *(const ushort4*)(rowp + tid * 8);
    ushort4 b0 = *(const ushort4*)(rowp + tid * 8 + 4);
    ushort4 a1 = *(const ushort4*)(rowp + 2048 + tid * 8);
    ushort4 b1 = *(const ushort4*)(rowp + 2048 + tid * 8 + 4);
    if (tid < 32) {
        float v = psum[(size_t)tid * BATCH_ + b];
        v += __shfl_xor(v, 1); v += __shfl_xor(v, 2); v += __shfl_xor(v, 4);
        v += __shfl_xor(v, 8); v += __shfl_xor(v, 16);
        if (tid == 0) sl = __logf(v);
    }
    __syncthreads();      // lse ready + all reads done before in-place overwrite
    float l = sl;
    float* orow = out + (size_t)b * VOC;
    int v0 = tid * 8;
    {
        float2 p;
        p.x = bf2f(a0.x) - l; p.y = bf2f(a0.y) - l; *(float2*)(orow + v0) = p;
        p.x = bf2f(a0.z) - l; p.y = bf2f(a0.w) - l; *(float2*)(orow + v0 + 2) = p;
        p.x = bf2f(b0.x) - l; p.y = bf2f(b0.y) - l; *(float2*)(orow + v0 + 4) = p;
        p.x = bf2f(b0.z) - l; p.y = bf2f(b0.w) - l; *(float2*)(orow + v0 + 6) = p;
    }
    int v1 = 2048 + tid * 8;
    {
        float2 p;
        p.x = bf2f(a1.x) - l; p.y = bf2f(a1.y) - l;
        if (v1 + 1 < VOC) *(float2*)(orow + v1) = p;
        p.x = bf2f(a1.z) - l; p.y = bf2f(a1.w) - l;
        if (v1 + 3 < VOC) *(float2*)(orow + v1 + 2) = p;
        p.x = bf2f(b1.x) - l; p.y = bf2f(b1.y) - l;
        if (v1 + 5 < VOC) *(float2*)(orow + v1 + 4) = p;
        p.x = bf2f(b1.z) - l; p.y = bf2f(b1.w) - l;
        if (v1 + 7 < VOC) *(float2*)(orow + v1 + 6) = p;
    }
}

extern "C" void kernel_launch(void* const* d_in, const int* in_sizes, int n_in,
                              void* d_out, int out_size, void* d_ws, size_t ws_size,
                              hipStream_t stream) {
    const int*   dw      = (const int*)d_in[0];
    const float* hidden  = (const float*)d_in[1];
    const float* enc     = (const float*)d_in[2];
    const float* emb     = (const float*)d_in[3];
    const float* aW      = (const float*)d_in[4];
    const float* ab      = (const float*)d_in[5];
    const float* comb_W  = (const float*)d_in[6];
    const float* comb_b  = (const float*)d_in[7];
    const float* W_ih    = (const float*)d_in[8];
    const float* b_ih    = (const float*)d_in[9];
    const float* W_hh    = (const float*)d_in[10];
    const float* b_hh    = (const float*)d_in[11];
    const float* out_W   = (const float*)d_in[12];
    const float* out_b   = (const float*)d_in[13];

    float* out = (float*)d_out;
    float* hnew_out = out + (size_t)BATCH_ * VOC;

    unsigned short* xcat = (unsigned short*)d_ws;
    unsigned short* xh   = xcat + (size_t)BATCH_ * 768;
    unsigned short* hnb  = xh + (size_t)BATCH_ * 768;
    float* psum          = (float*)(hnb + (size_t)BATCH_ * 256);   // 32 * BATCH floats
    float* obp           = psum + (size_t)32 * BATCH_;             // 4096 floats
    unsigned short* cwb  = (unsigned short*)(obp + 4096);
    unsigned short* wg2  = cwb + 512 * 768;
    unsigned short* owb  = wg2 + 1024 * 768;
    float* bg            = (float*)(owb + 4096 * 256);

    k_prep<<<4096, 256, 0, stream>>>(comb_W, W_ih, W_hh, out_W, b_ih, b_hh, out_b,
                                     cwb, wg2, owb, bg, obp);
    k_attn<<<BATCH_ / 32, 256, 0, stream>>>(dw, hidden, enc, emb, aW, ab, xcat, xh);
    k_combine<<<1024, 256, 0, stream>>>(xcat, cwb, comb_b, xh);
    k_gru<<<2048, 256, 0, stream>>>(xh, wg2, bg, hidden, hnew_out, hnb);
    k_logit<<<8192, 256, 0, stream>>>(hnb, owb, obp, (unsigned short*)out, psum);
    k_out2<<<BATCH_, 256, 0, stream>>>(psum, out);
}

// Round 14
// 680.672 us; speedup vs baseline: 1.4457x; 1.0570x over previous
//
#include <hip/hip_runtime.h>

typedef __bf16 bf16x8 __attribute__((ext_vector_type(8)));
typedef unsigned short u16x8 __attribute__((ext_vector_type(8)));
typedef float  f32x4  __attribute__((ext_vector_type(4)));

#define BATCH_ 32768
#define VOC 4094
#define LGT_STRIDE 8188   // ushorts per out row (4094 f32)

// native f32->bf16 (RNE) — compiler emits v_cvt_pk_bf16_f32 for pairs (m240:
// hand-rolled bit-manip defeats this and costs ~3-4 VALU/elem)
__device__ inline unsigned short f2bf(float f) {
    __bf16 h = (__bf16)f;
    return __builtin_bit_cast(unsigned short, h);
}
__device__ inline float bf2f(unsigned short u) {
    unsigned int v = ((unsigned int)u) << 16;
    return __builtin_bit_cast(float, v);
}
__device__ inline f32x4 mfma16(bf16x8 a, bf16x8 b, f32x4 c) {
    return __builtin_amdgcn_mfma_f32_16x16x32_bf16(a, b, c, 0, 0, 0);
}
__device__ inline void gload16(const void* g, void* l) {
    __builtin_amdgcn_global_load_lds(
        (const __attribute__((address_space(1))) void*)(g),
        (__attribute__((address_space(3))) void*)(l),
        16, 0, 0);
}
__device__ inline bf16x8 pack8(float4 a, float4 b) {
    bf16x8 r;
    r[0] = (__bf16)a.x; r[1] = (__bf16)a.y; r[2] = (__bf16)a.z; r[3] = (__bf16)a.w;
    r[4] = (__bf16)b.x; r[5] = (__bf16)b.y; r[6] = (__bf16)b.z; r[7] = (__bf16)b.w;
    return r;
}

// ---------------- K0: weight prep -> pre-swizzled 16KB chunk images (BK=64) ----------------
__global__ __launch_bounds__(256) void k_prep(
    const float* __restrict__ comb_W, const float* __restrict__ W_ih,
    const float* __restrict__ W_hh, const float* __restrict__ out_W,
    const float* __restrict__ b_ih, const float* __restrict__ b_hh,
    const float* __restrict__ out_b,
    unsigned short* __restrict__ cwb, unsigned short* __restrict__ wg2,
    unsigned short* __restrict__ owb, float* __restrict__ bg,
    float* __restrict__ obp) {
    int i = blockIdx.x * 256 + threadIdx.x;      // grid covers 1,048,576
    if (i < 512 * 768) {
        int n = i / 768, k = i - n * 768;
        int by = n >> 7, r = n & 127, kc = k >> 6, kl = k & 63;
        int dst = (by * 12 + kc) * 8192 + r * 64 + (((kl >> 3) ^ (r & 7)) << 3) + (kl & 7);
        cwb[dst] = f2bf(comb_W[i]);
    }
    if (i < 1024 * 768) {
        int row = i / 768, k = i - row * 768;
        int hgrp = row >> 6, g = (row >> 4) & 3, hl = row & 15;
        int h = hgrp * 16 + hl;
        float v;
        if (g == 0) v = (k < 512) ? W_ih[(size_t)h * 512 + k] : W_hh[(size_t)h * 256 + (k - 512)];
        else if (g == 1) v = (k < 512) ? W_ih[(size_t)(256 + h) * 512 + k] : W_hh[(size_t)(256 + h) * 256 + (k - 512)];
        else if (g == 2) v = (k < 512) ? W_ih[(size_t)(512 + h) * 512 + k] : 0.f;
        else v = (k < 512) ? 0.f : W_hh[(size_t)(512 + h) * 256 + (k - 512)];
        int by = row >> 7, r = row & 127, kc = k >> 6, kl = k & 63;
        int dst = (by * 12 + kc) * 8192 + r * 64 + (((kl >> 3) ^ (r & 7)) << 3) + (kl & 7);
        wg2[dst] = f2bf(v);
    }
    if (i < 4096 * 256) {
        int n = i >> 8, k = i & 255;
        int by = n >> 7, r = n & 127, kc = k >> 6, kl = k & 63;
        int dst = (by * 4 + kc) * 8192 + r * 64 + (((kl >> 3) ^ (r & 7)) << 3) + (kl & 7);
        owb[dst] = (n < VOC) ? f2bf(out_W[i]) : (unsigned short)0;
    }
    if (i < 1024) {
        float v = (i < 512) ? (b_ih[i] + b_hh[i]) : ((i < 768) ? b_ih[i] : b_hh[i - 256]);
        bg[i] = v;
    }
    if (i < 4096) obp[i] = (i < VOC) ? out_b[i] : -1.0e30f;
}

// ---------------- K1: attention (32 rows / block, 4 waves, 1024 blocks) ----------------
__global__ __launch_bounds__(256) void k_attn(
    const int* __restrict__ dw, const float* __restrict__ hidden,
    const float* __restrict__ enc, const float* __restrict__ emb,
    const float* __restrict__ aW, const float* __restrict__ ab,
    unsigned short* __restrict__ xcat, unsigned short* __restrict__ xh) {
    __shared__ __align__(16) unsigned short sA1[16 * 264];  // aW[:, :256] bf16, rows>=9 zero
    __shared__ __align__(16) unsigned short sA2[16 * 264];  // aW[:, 256:] bf16
    __shared__ float sU[32][17];
    __shared__ float sW[32][17];
    __shared__ float sAB[16];
    int tid = threadIdx.x, w = tid >> 6, lane = tid & 63;
    int lo = lane & 15, hi = lane >> 4;
    int B0 = blockIdx.x * 32;

    for (int i = tid; i < 16 * 256; i += 256) {
        int m = i >> 8, k = i & 255;
        float v1 = (m < 9) ? aW[m * 512 + k] : 0.f;
        float v2 = (m < 9) ? aW[m * 512 + 256 + k] : 0.f;
        sA1[m * 264 + k] = f2bf(v1);
        sA2[m * 264 + k] = f2bf(v2);
    }
    if (tid < 16) sAB[tid] = (tid < 9) ? ab[tid] : 0.f;
    if (tid < 32) {
#pragma unroll
        for (int m = 0; m < 16; m++) sW[tid][m] = 0.f;
    }
    __syncthreads();

    // ---- phase 1: u tiles (waves 0,1; b = B0 + w*16 + lo) ----
    if (w < 2) {
        const float* hrow = hidden + (size_t)(B0 + w * 16 + lo) * 256 + 8 * hi;
        f32x4 uacc = {};
#pragma unroll
        for (int ks = 0; ks < 8; ks++) {
            float4 f0 = *(const float4*)(hrow + ks * 32);
            float4 f1 = *(const float4*)(hrow + ks * 32 + 4);
            bf16x8 Bf = pack8(f0, f1);
            bf16x8 Af = *(const bf16x8*)(sA2 + lo * 264 + ks * 32 + 8 * hi);
            uacc = mfma16(Af, Bf, uacc);
        }
#pragma unroll
        for (int r = 0; r < 4; r++) {
            int m = hi * 4 + r;
            sU[w * 16 + lo][m] = uacc[r] + sAB[m];
        }
    }
    __syncthreads();

    // ---- phase 2: 18 tiles (288 = 32b x 9l rows), round-robin t = w + 4*t8 ----
    bf16x8 Asc[8];
#pragma unroll
    for (int ks = 0; ks < 8; ks++)
        Asc[ks] = *(const bf16x8*)(sA1 + lo * 264 + ks * 32 + 8 * hi);
    const float* encF = enc + (size_t)B0 * 9 * 256;
#pragma unroll
    for (int t8 = 0; t8 < 5; t8++) {
        int t = w + t8 * 4;
        if (t < 18) {
            int rowloc = t * 16 + lo;              // flat (b,l) within block
            const float* er = encF + (size_t)rowloc * 256 + 8 * hi;
            f32x4 acc = {};
#pragma unroll
            for (int ks = 0; ks < 8; ks++) {
                float4 f0 = *(const float4*)(er + ks * 32);
                float4 f1 = *(const float4*)(er + ks * 32 + 4);
                bf16x8 Bf = pack8(f0, f1);
                acc = mfma16(Asc[ks], Bf, acc);
            }
            int bloc = rowloc / 9;
            float s[4];
            float mx = -1.0e30f;
#pragma unroll
            for (int r = 0; r < 4; r++) {
                int m = hi * 4 + r;
                s[r] = acc[r] + sU[bloc][m];
                if (m < 9) mx = fmaxf(mx, s[r]);
            }
            mx = fmaxf(mx, __shfl_xor(mx, 16));
            mx = fmaxf(mx, __shfl_xor(mx, 32));
            float ex[4], sm = 0.f;
#pragma unroll
            for (int r = 0; r < 4; r++) {
                int m = hi * 4 + r;
                ex[r] = (m < 9) ? __expf(s[r] - mx) : 0.f;
                sm += ex[r];
            }
            sm += __shfl_xor(sm, 16);
            sm += __shfl_xor(sm, 32);
            float inv = 1.f / sm;
#pragma unroll
            for (int r = 0; r < 4; r++) {
                int m = hi * 4 + r;
                if (m < 9) atomicAdd(&sW[bloc][m], ex[r] * inv);
            }
        }
    }
    __syncthreads();

    // ---- phase 3: wave-per-row, fully coalesced (1KB/instr enc reads), 8 rows/wave ----
    for (int i = 0; i < 8; i++) {
        int bl = w * 8 + i;
        size_t b = (size_t)(B0 + bl);
        float wsv[9];
#pragma unroll
        for (int m = 0; m < 9; m++) wsv[m] = sW[bl][m];
        const float* encR = enc + b * (9 * 256) + 4 * lane;
        float c0 = 0.f, c1 = 0.f, c2 = 0.f, c3 = 0.f;
#pragma unroll
        for (int m = 0; m < 9; m++) {
            float4 e4 = *(const float4*)(encR + m * 256);
            c0 += wsv[m] * e4.x; c1 += wsv[m] * e4.y;
            c2 += wsv[m] * e4.z; c3 += wsv[m] * e4.w;
        }
        ushort4 cb; cb.x = f2bf(c0); cb.y = f2bf(c1); cb.z = f2bf(c2); cb.w = f2bf(c3);
        *(ushort4*)(xcat + b * 768 + 512 + 4 * lane) = cb;
        float4 h4 = *(const float4*)(hidden + b * 256 + 4 * lane);
        ushort4 hb; hb.x = f2bf(h4.x); hb.y = f2bf(h4.y); hb.z = f2bf(h4.z); hb.w = f2bf(h4.w);
        *(ushort4*)(xh + b * 768 + 512 + 4 * lane) = hb;
        int word = dw[b];
        const float* er2 = emb + (size_t)word * 512 + 8 * lane;
        float4 e0 = *(const float4*)er2;
        float4 e1 = *(const float4*)(er2 + 4);
        ushort4 w0; w0.x = f2bf(e0.x); w0.y = f2bf(e0.y); w0.z = f2bf(e0.z); w0.w = f2bf(e0.w);
        ushort4 w1; w1.x = f2bf(e1.x); w1.y = f2bf(e1.y); w1.z = f2bf(e1.z); w1.w = f2bf(e1.w);
        *(ushort4*)(xcat + b * 768 + 8 * lane) = w0;
        *(ushort4*)(xcat + b * 768 + 8 * lane + 4) = w1;
    }
}

// ---------------- K2: x = relu(xcat @ comb_W^T + comb_b) -> xh[:,0:512] ----------------
// grid 1024 = 8 xcd x 32 bx x 4 by; tile 128M x 128N; BK=64 dbuf (2x16KB), M-rep 2.
__global__ __launch_bounds__(256, 4) void k_combine(
    const unsigned short* __restrict__ xcat, const unsigned short* __restrict__ cwb,
    const float* __restrict__ comb_b, unsigned short* __restrict__ xh) {
    __shared__ __align__(16) char smem[32768];
    int wgid = blockIdx.x;
    int xcd = wgid & 7, slot = wgid >> 3;
    int bx = xcd * 32 + (slot & 31), by = slot >> 5;     // bx<256, by<4
    int tid = threadIdx.x, w = tid >> 6, lane = tid & 63;
    int lo = lane & 15, hi = lane >> 4;
    int bm0 = bx * 128, n0 = by * 128;
    const __bf16* A = (const __bf16*)xcat;
    const char* gb = (const char*)cwb + (size_t)by * 12 * 16384;
    size_t ar = (size_t)(bm0 + w * 32 + lo) * 768 + 8 * hi;
    f32x4 acc[2][8] = {};
    bf16x8 Afb[2][2][2];
#pragma unroll
    for (int mf = 0; mf < 2; mf++)
#pragma unroll
        for (int ks = 0; ks < 2; ks++)
            Afb[0][mf][ks] = *(const bf16x8*)(A + ar + mf * 16 * 768 + ks * 32);
    for (int it = 0; it < 4; it++) {
        int uo = (w * 4 + it) << 10;
        gload16(gb + uo + lane * 16, smem + uo);
    }
    __syncthreads();
#pragma unroll
    for (int c = 0; c < 12; c++) {
        int cur = c & 1;
        if (c < 11) {
            const char* gc = gb + (size_t)(c + 1) * 16384;
            char* lb = smem + (cur ^ 1) * 16384;
            for (int it = 0; it < 4; it++) {
                int uo = (w * 4 + it) << 10;
                gload16(gc + uo + lane * 16, lb + uo);
            }
#pragma unroll
            for (int mf = 0; mf < 2; mf++)
#pragma unroll
                for (int ks = 0; ks < 2; ks++)
                    Afb[cur ^ 1][mf][ks] = *(const bf16x8*)(A + ar + mf * 16 * 768 + (c + 1) * 64 + ks * 32);
        }
        const char* cb = smem + cur * 16384;
#pragma unroll
        for (int ks = 0; ks < 2; ks++)
#pragma unroll
            for (int nf = 0; nf < 8; nf++) {
                int row = nf * 16 + lo;
                bf16x8 bfr = *(const bf16x8*)(cb + row * 128 + (((ks * 4 + hi) ^ (lo & 7)) << 4));
                acc[0][nf] = mfma16(Afb[cur][0][ks], bfr, acc[0][nf]);
                acc[1][nf] = mfma16(Afb[cur][1][ks], bfr, acc[1][nf]);
            }
        __syncthreads();
    }
#pragma unroll
    for (int mf = 0; mf < 2; mf++)
#pragma unroll
        for (int nf = 0; nf < 8; nf++) {
            int col = n0 + nf * 16 + lo;
            float cb = comb_b[col];
#pragma unroll
            for (int r = 0; r < 4; r++) {
                int row = bm0 + w * 32 + mf * 16 + hi * 4 + r;
                xh[(size_t)row * 768 + col] = f2bf(fmaxf(acc[mf][nf][r] + cb, 0.f));
            }
        }
}

// ---------------- K3: GRU gates GEMM (interleaved wg2) + in-register epilogue ----------------
// grid 2048 = 8 xcd x 32 bx x 8 by; tile 128M x 128N (32h x 4gates); BK=64 dbuf, M-rep 2.
__global__ __launch_bounds__(256, 4) void k_gru(
    const unsigned short* __restrict__ xh, const unsigned short* __restrict__ wg2,
    const float* __restrict__ bg, const float* __restrict__ hidden,
    float* __restrict__ hnew_out, unsigned short* __restrict__ hnb) {
    __shared__ __align__(16) char smem[32768];
    int wgid = blockIdx.x;
    int xcd = wgid & 7, slot = wgid >> 3;
    int bx = xcd * 32 + (slot & 31), by = slot >> 5;     // bx<256, by<8
    int tid = threadIdx.x, w = tid >> 6, lane = tid & 63;
    int lo = lane & 15, hi = lane >> 4;
    int bm0 = bx * 128;
    int h00 = by * 32;
    const __bf16* A = (const __bf16*)xh;
    const char* gb = (const char*)wg2 + (size_t)by * 12 * 16384;
    size_t ar = (size_t)(bm0 + w * 32 + lo) * 768 + 8 * hi;
    f32x4 acc[2][8] = {};
    bf16x8 Afb[2][2][2];
#pragma unroll
    for (int mf = 0; mf < 2; mf++)
#pragma unroll
        for (int ks = 0; ks < 2; ks++)
            Afb[0][mf][ks] = *(const bf16x8*)(A + ar + mf * 16 * 768 + ks * 32);
    for (int it = 0; it < 4; it++) {
        int uo = (w * 4 + it) << 10;
        gload16(gb + uo + lane * 16, smem + uo);
    }
    __syncthreads();
#pragma unroll
    for (int c = 0; c < 12; c++) {
        int cur = c & 1;
        if (c < 11) {
            const char* gc = gb + (size_t)(c + 1) * 16384;
            char* lb = smem + (cur ^ 1) * 16384;
            for (int it = 0; it < 4; it++) {
                int uo = (w * 4 + it) << 10;
                gload16(gc + uo + lane * 16, lb + uo);
            }
#pragma unroll
            for (int mf = 0; mf < 2; mf++)
#pragma unroll
                for (int ks = 0; ks < 2; ks++)
                    Afb[cur ^ 1][mf][ks] = *(const bf16x8*)(A + ar + mf * 16 * 768 + (c + 1) * 64 + ks * 32);
        }
        const char* cb = smem + cur * 16384;
#pragma unroll
        for (int ks = 0; ks < 2; ks++)
#pragma unroll
            for (int nf = 0; nf < 8; nf++) {
                int row = nf * 16 + lo;
                bf16x8 bfr = *(const bf16x8*)(cb + row * 128 + (((ks * 4 + hi) ^ (lo & 7)) << 4));
                acc[0][nf] = mfma16(Afb[cur][0][ks], bfr, acc[0][nf]);
                acc[1][nf] = mfma16(Afb[cur][1][ks], bfr, acc[1][nf]);
            }
        __syncthreads();
    }
    // epilogue: acc[mf][hgrp*4 + g] holds gate g for h-col = h00 + hgrp*16 + lo
#pragma unroll
    for (int mf = 0; mf < 2; mf++)
#pragma unroll
        for (int hgrp = 0; hgrp < 2; hgrp++) {
            int col = h00 + hgrp * 16 + lo;
            float br = bg[col], bz = bg[256 + col], bi = bg[512 + col], bh = bg[768 + col];
#pragma unroll
            for (int r = 0; r < 4; r++) {
                int row = bm0 + w * 32 + mf * 16 + hi * 4 + r;
                float rr = 1.f / (1.f + __expf(-(acc[mf][hgrp * 4 + 0][r] + br)));
                float zz = 1.f / (1.f + __expf(-(acc[mf][hgrp * 4 + 1][r] + bz)));
                float nn = tanhf(acc[mf][hgrp * 4 + 2][r] + bi + rr * (acc[mf][hgrp * 4 + 3][r] + bh));
                float hp = hidden[(size_t)row * 256 + col];
                float hn = zz * (hp - nn) + nn;
                hnew_out[(size_t)row * 256 + col] = hn;
                hnb[(size_t)row * 256 + col] = f2bf(hn);
            }
        }
}

// ---------------- K4: vocab GEMM (once): bf16 logits into out rows + psum ----------------
// grid 8192 = 8 xcd x 32 bx x 32 by; tile 128M x 128N; K=256 = 4 BK=64 dbuf chunks, M-rep 2.
__global__ __launch_bounds__(256, 4) void k_logit(
    const unsigned short* __restrict__ hnb, const unsigned short* __restrict__ owb,
    const float* __restrict__ obp, unsigned short* __restrict__ lgt,
    float* __restrict__ psum) {
    __shared__ __align__(16) char smem[34816];   // dbuf 2x16KB; T [128][136] ushort = 34816B
    int wgid = blockIdx.x;
    int xcd = wgid & 7, slot = wgid >> 3;
    int bx = xcd * 32 + (slot & 31), by = slot >> 5;     // bx<256, by<32
    int tid = threadIdx.x, w = tid >> 6, lane = tid & 63;
    int lo = lane & 15, hi = lane >> 4;
    int bm0 = bx * 128, n0 = by * 128;
    const __bf16* A = (const __bf16*)hnb;
    const char* gb = (const char*)owb + (size_t)by * 4 * 16384;
    size_t ar = (size_t)(bm0 + w * 32 + lo) * 256 + 8 * hi;
    f32x4 acc[2][8] = {};
    bf16x8 Afb[2][2][2];
#pragma unroll
    for (int mf = 0; mf < 2; mf++)
#pragma unroll
        for (int ks = 0; ks < 2; ks++)
            Afb[0][mf][ks] = *(const bf16x8*)(A + ar + mf * 16 * 256 + ks * 32);
    for (int it = 0; it < 4; it++) {
        int uo = (w * 4 + it) << 10;
        gload16(gb + uo + lane * 16, smem + uo);
    }
    __syncthreads();
#pragma unroll
    for (int c = 0; c < 4; c++) {
        int cur = c & 1;
        if (c < 3) {
            const char* gc = gb + (size_t)(c + 1) * 16384;
            char* lb = smem + (cur ^ 1) * 16384;
            for (int it = 0; it < 4; it++) {
                int uo = (w * 4 + it) << 10;
                gload16(gc + uo + lane * 16, lb + uo);
            }
#pragma unroll
            for (int mf = 0; mf < 2; mf++)
#pragma unroll
                for (int ks = 0; ks < 2; ks++)
                    Afb[cur ^ 1][mf][ks] = *(const bf16x8*)(A + ar + mf * 16 * 256 + (c + 1) * 64 + ks * 32);
        }
        const char* cb = smem + cur * 16384;
#pragma unroll
        for (int ks = 0; ks < 2; ks++)
#pragma unroll
            for (int nf = 0; nf < 8; nf++) {
                int row = nf * 16 + lo;
                bf16x8 bfr = *(const bf16x8*)(cb + row * 128 + (((ks * 4 + hi) ^ (lo & 7)) << 4));
                acc[0][nf] = mfma16(Afb[cur][0][ks], bfr, acc[0][nf]);
                acc[1][nf] = mfma16(Afb[cur][1][ks], bfr, acc[1][nf]);
            }
        __syncthreads();
    }

    unsigned short* T = (unsigned short*)smem;   // [128][136]
    float se[2][4] = {};
#pragma unroll
    for (int mf = 0; mf < 2; mf++)
#pragma unroll
        for (int nf = 0; nf < 8; nf++) {
            int col = n0 + nf * 16 + lo;
            float ob = obp[col];
#pragma unroll
            for (int r = 0; r < 4; r++) {
                float lg = acc[mf][nf][r] + ob;
                se[mf][r] += __expf(lg);
                T[(w * 32 + mf * 16 + hi * 4 + r) * 136 + nf * 16 + lo] = f2bf(lg);
            }
        }
#pragma unroll
    for (int mf = 0; mf < 2; mf++)
#pragma unroll
        for (int r = 0; r < 4; r++) {
            float v = se[mf][r];
            v += __shfl_xor(v, 1); v += __shfl_xor(v, 2);
            v += __shfl_xor(v, 4); v += __shfl_xor(v, 8);
            se[mf][r] = v;
        }
    if (lo == 0) {
#pragma unroll
        for (int mf = 0; mf < 2; mf++)
#pragma unroll
            for (int r = 0; r < 4; r++)
                psum[(size_t)by * BATCH_ + bm0 + w * 32 + mf * 16 + hi * 4 + r] = se[mf][r];
    }
    __syncthreads();
#pragma unroll
    for (int it = 0; it < 8; it++) {
        int t = it * 256 + tid;
        int row = t >> 4, ch = t & 15;
        ushort4 a = *(ushort4*)(T + row * 136 + ch * 8);
        ushort4 b = *(ushort4*)(T + row * 136 + ch * 8 + 4);
        size_t base = (size_t)(bm0 + row) * LGT_STRIDE + n0 + ch * 8;
        *(ushort4*)(lgt + base) = a;
        *(ushort4*)(lgt + base + 4) = b;
    }
}

// ---------------- K5: fused lse + streaming out[b][v] = bf16logit - lse (in-place) ----------------
__global__ __launch_bounds__(256) void k_out2(
    const float* __restrict__ psum, float* __restrict__ out) {
    __shared__ float sl;
    int b = blockIdx.x, tid = threadIdx.x;
    const unsigned short* rowp = (const unsigned short*)(out + (size_t)b * VOC);
    ushort4 a0 = *(const ushort4*)(rowp + tid * 8);
    ushort4 b0 = *(const ushort4*)(rowp + tid * 8 + 4);
    ushort4 a1 = *(const ushort4*)(rowp + 2048 + tid * 8);
    ushort4 b1 = *(const ushort4*)(rowp + 2048 + tid * 8 + 4);
    if (tid < 32) {
        float v = psum[(size_t)tid * BATCH_ + b];
        v += __shfl_xor(v, 1); v += __shfl_xor(v, 2); v += __shfl_xor(v, 4);
        v += __shfl_xor(v, 8); v += __shfl_xor(v, 16);
        if (tid == 0) sl = __logf(v);
    }
    __syncthreads();      // lse ready + all reads done before in-place overwrite
    float l = sl;
    float* orow = out + (size_t)b * VOC;
    int v0 = tid * 8;
    {
        float2 p;
        p.x = bf2f(a0.x) - l; p.y = bf2f(a0.y) - l; *(float2*)(orow + v0) = p;
        p.x = bf2f(a0.z) - l; p.y = bf2f(a0.w) - l; *(float2*)(orow + v0 + 2) = p;
        p.x = bf2f(b0.x) - l; p.y = bf2f(b0.y) - l; *(float2*)(orow + v0 + 4) = p;
        p.x = bf2f(b0.z) - l; p.y = bf2f(b0.w) - l; *(float2*)(orow + v0 + 6) = p;
    }
    int v1 = 2048 + tid * 8;
    {
        float2 p;
        p.x = bf2f(a1.x) - l; p.y = bf2f(a1.y) - l;
        if (v1 + 1 < VOC) *(float2*)(orow + v1) = p;
        p.x = bf2f(a1.z) - l; p.y = bf2f(a1.w) - l;
        if (v1 + 3 < VOC) *(float2*)(orow + v1 + 2) = p;
        p.x = bf2f(b1.x) - l; p.y = bf2f(b1.y) - l;
        if (v1 + 5 < VOC) *(float2*)(orow + v1 + 4) = p;
        p.x = bf2f(b1.z) - l; p.y = bf2f(b1.w) - l;
        if (v1 + 7 < VOC) *(float2*)(orow + v1 + 6) = p;
    }
}

extern "C" void kernel_launch(void* const* d_in, const int* in_sizes, int n_in,
                              void* d_out, int out_size, void* d_ws, size_t ws_size,
                              hipStream_t stream) {
    const int*   dw      = (const int*)d_in[0];
    const float* hidden  = (const float*)d_in[1];
    const float* enc     = (const float*)d_in[2];
    const float* emb     = (const float*)d_in[3];
    const float* aW      = (const float*)d_in[4];
    const float* ab      = (const float*)d_in[5];
    const float* comb_W  = (const float*)d_in[6];
    const float* comb_b  = (const float*)d_in[7];
    const float* W_ih    = (const float*)d_in[8];
    const float* b_ih    = (const float*)d_in[9];
    const float* W_hh    = (const float*)d_in[10];
    const float* b_hh    = (const float*)d_in[11];
    const float* out_W   = (const float*)d_in[12];
    const float* out_b   = (const float*)d_in[13];

    float* out = (float*)d_out;
    float* hnew_out = out + (size_t)BATCH_ * VOC;

    unsigned short* xcat = (unsigned short*)d_ws;
    unsigned short* xh   = xcat + (size_t)BATCH_ * 768;
    unsigned short* hnb  = xh + (size_t)BATCH_ * 768;
    float* psum          = (float*)(hnb + (size_t)BATCH_ * 256);   // 32 * BATCH floats
    float* obp           = psum + (size_t)32 * BATCH_;             // 4096 floats
    unsigned short* cwb  = (unsigned short*)(obp + 4096);
    unsigned short* wg2  = cwb + 512 * 768;
    unsigned short* owb  = wg2 + 1024 * 768;
    float* bg            = (float*)(owb + 4096 * 256);

    k_prep<<<4096, 256, 0, stream>>>(comb_W, W_ih, W_hh, out_W, b_ih, b_hh, out_b,
                                     cwb, wg2, owb, bg, obp);
    k_attn<<<BATCH_ / 32, 256, 0, stream>>>(dw, hidden, enc, emb, aW, ab, xcat, xh);
    k_combine<<<1024, 256, 0, stream>>>(xcat, cwb, comb_b, xh);
    k_gru<<<2048, 256, 0, stream>>>(xh, wg2, bg, hidden, hnew_out, hnb);
    k_logit<<<8192, 256, 0, stream>>>(hnb, owb, obp, (unsigned short*)out, psum);
    k_out2<<<BATCH_, 256, 0, stream>>>(psum, out);
}